// Round 1
// baseline (33643.271 us; speedup 1.0000x reference)
//
#include <hip/hip_runtime.h>
#include <cstdint>
#include <cstddef>

#define BATCH       65536
#define LDSW        36          // padded LDS row stride (16B-aligned rows)
#define NCHEB       26          // Chebyshev terms for log on [CALPHA, CBETA]
#define CALPHA      0.2f
#define CBETA       6.0f
#define NS_ITERS    6           // Newton-Schulz sqrt iterations
#define EXP_TERMS   12          // Taylor terms for matrix exp
#define MAIN_BLOCKS 4096        // main kernels: 4096 blocks x 64 threads, 16 elems each

// ws float offsets
#define OFF_MEAN0   0
#define OFF_INVS0   1024
#define OFF_S0      2048
#define OFF_LOGAVG  3072
#define OFF_INVS    4096
#define OFF_SSQRT   5120
#define OFF_VAR     6144
#define OFF_P       6145
#define OFF_CHEB    6152        // 26 floats

typedef float (*LdsMat)[LDSW];

// ---------- per-lane helpers (one wave = one 32x32 matrix) ----------
// Lane layout: lane = 32*h + c; lane owns output entries (r=16h+i, c), i=0..15.

__device__ __forceinline__ float dotrow36(const float* Arow, const float* v) {
  float s = 0.f;
#pragma unroll
  for (int j = 0; j < 8; ++j) {
    float4 a = *reinterpret_cast<const float4*>(Arow + 4 * j);
    s = fmaf(a.x, v[4 * j + 0], s);
    s = fmaf(a.y, v[4 * j + 1], s);
    s = fmaf(a.z, v[4 * j + 2], s);
    s = fmaf(a.w, v[4 * j + 3], s);
  }
  return s;
}

// own16 holds rows [16h,16h+16) of a column; build the full 32-row column.
__device__ __forceinline__ void build_full(const float* own16, float* full32, int h) {
#pragma unroll
  for (int i = 0; i < 16; ++i) {
    float o = __shfl_xor(own16[i], 32);
    full32[i]      = (h == 0) ? own16[i] : o;
    full32[16 + i] = (h == 0) ? o : own16[i];
  }
}

// load a row-major 32x32 matrix from global into LDS [32][LDSW]
__device__ __forceinline__ void ldmat(const float* __restrict__ g, float (*M)[LDSW], int lane) {
#pragma unroll
  for (int e = 0; e < 4; ++e) {
    int idx = e * 256 + lane * 4;
    float4 v = *reinterpret_cast<const float4*>(g + idx);
    *reinterpret_cast<float4*>(&M[idx >> 5][idx & 31]) = v;
  }
}

// M1 = x (in), M2 = S (symmetric). Computes Ytilde = g*(S x S) - m*I into M1.
// Returns tFull = Ytilde col c (all 32 rows), tOwn = own-half values.
__device__ __forceinline__ void whiten(float (*M1)[LDSW], const float (*M2)[LDSW],
                                       int lane, float* tFull, float* tOwn) {
  const int h = lane >> 5, c = lane & 31;
  float bcol[32];
#pragma unroll
  for (int j = 0; j < 8; ++j) {
    float4 v = *reinterpret_cast<const float4*>(&M2[c][4 * j]);  // S col c (= row c, symmetric)
    bcol[4 * j + 0] = v.x; bcol[4 * j + 1] = v.y; bcol[4 * j + 2] = v.z; bcol[4 * j + 3] = v.w;
  }
  float uo[16];                                                  // U = x*S, col c, own rows
#pragma unroll
  for (int i = 0; i < 16; ++i) uo[i] = dotrow36(&M1[16 * h + i][0], bcol);
  __syncthreads();                                               // all x-reads of M1 done
  float uf[32];
  build_full(uo, uf, h);
  const float g = 2.f / (CBETA - CALPHA);
  const float m = (CALPHA + CBETA) / (CBETA - CALPHA);
#pragma unroll
  for (int i = 0; i < 16; ++i) {
    int r = 16 * h + i;
    float y = dotrow36(&M2[r][0], uf);                           // (S*U)[r][c]
    tOwn[i] = fmaf(y, g, (r == c) ? -m : 0.f);
  }
#pragma unroll
  for (int i = 0; i < 16; ++i) M1[16 * h + i][c] = tOwn[i];
  __syncthreads();
  build_full(tOwn, tFull, h);
}

// L[r][c] (own half) of cheb-log(Ytilde). M1 = Ytilde; tA = Ytilde col (T1); tOwn = own half.
template <bool ACCUM>
__device__ __forceinline__ void cheb_log_col(const float (*M1)[LDSW], float* tA, const float* tOwn,
                                             int lane, const float* __restrict__ chg, float* Lout) {
  const int h = lane >> 5, c = lane & 31;
  const float c0 = chg[0], c1 = chg[1];
  float pOwn[16];
#pragma unroll
  for (int i = 0; i < 16; ++i) {
    int r = 16 * h + i;
    float t0 = (r == c) ? 1.f : 0.f;
    pOwn[i] = t0;
    float val = fmaf(c1, tOwn[i], c0 * t0);
    if (ACCUM) Lout[i] += val; else Lout[i] = val;
  }
  for (int k = 2; k < NCHEB; ++k) {
    const float ck = chg[k];
    float tn[16];
#pragma unroll
    for (int i = 0; i < 16; ++i) {
      float s = dotrow36(&M1[16 * h + i][0], tA);                // (Y~ * T_{k-1})[r][c]
      tn[i] = fmaf(2.f, s, -pOwn[i]);                            // T_k = 2 Y~ T_{k-1} - T_{k-2}
      Lout[i] = fmaf(ck, tn[i], Lout[i]);
    }
#pragma unroll
    for (int i = 0; i < 16; ++i) pOwn[i] = (h == 0) ? tA[i] : tA[16 + i];
    build_full(tn, tA, h);
  }
}

// ---------- tiny-kernel helpers (single block, 64 threads) ----------

__device__ void mm64(float (*D)[LDSW], const float (*A)[LDSW], const float (*Bm)[LDSW], int lane) {
  const int h = lane >> 5, c = lane & 31;
  float bcol[32];
#pragma unroll
  for (int k = 0; k < 32; ++k) bcol[k] = Bm[k][c];
  float o[16];
#pragma unroll
  for (int i = 0; i < 16; ++i) o[i] = dotrow36(&A[16 * h + i][0], bcol);
  __syncthreads();
#pragma unroll
  for (int i = 0; i < 16; ++i) D[16 * h + i][c] = o[i];
  __syncthreads();
}

// coupled Newton-Schulz: Y->A^(1/2), Z->A^(-1/2), A=Y initially (spec near 1)
__device__ void ns_sqrt(LdsMat& Y, LdsMat& Z, LdsMat& Ya, LdsMat& Za, LdsMat T, int lane) {
  const int h = lane >> 5, c = lane & 31;
  for (int it = 0; it < NS_ITERS; ++it) {
    mm64(T, Z, Y, lane);                      // T = Z*Y
#pragma unroll
    for (int i = 0; i < 16; ++i) {
      int r = 16 * h + i;
      T[r][c] = ((r == c) ? 1.5f : 0.f) - 0.5f * T[r][c];
    }
    __syncthreads();
    mm64(Ya, Y, T, lane);                     // Y' = Y*T
    mm64(Za, T, Z, lane);                     // Z' = T*Z
    LdsMat t1 = Y; Y = Ya; Ya = t1;
    LdsMat t2 = Z; Z = Za; Za = t2;
  }
}

// ---------- kernels ----------

// mean over batch -> ws[OFF_MEAN0] (raw sum; divided later)
extern "C" __global__ void __launch_bounds__(256)
spdbn_kA(const float* __restrict__ x, float* __restrict__ wsf) {
  const int e  = (blockIdx.x & 3) * 256 + threadIdx.x;   // matrix entry 0..1023
  const int bs = blockIdx.x >> 2;                        // 0..1023
  float acc = 0.f;
  for (int t = 0; t < 64; ++t)
    acc += x[(size_t)(bs + 1024 * t) * 1024 + e];
  atomicAdd(&wsf[OFF_MEAN0 + e], acc);
}

// mean0^{±1/2} via Newton-Schulz; Chebyshev coefficients of log via 64-pt quadrature
extern "C" __global__ void __launch_bounds__(64)
spdbn_kS1(float* __restrict__ wsf) {
  __shared__ alignas(16) float W0[32][LDSW], W1[32][LDSW], W2[32][LDSW], W3[32][LDSW], W4[32][LDSW];
  const int lane = threadIdx.x, h = lane >> 5, c = lane & 31;
  float sacc = 0.f;
#pragma unroll
  for (int k = 0; k < 32; ++k) sacc += wsf[OFF_MEAN0 + 33 * k];
  const float cN = sacc / (32.f * (float)BATCH);         // trace(mean0)/32
  const float scaleA = 32.f / sacc;                      // 1/(B*cN)
#pragma unroll
  for (int i = 0; i < 16; ++i) {
    int r = 16 * h + i;
    W1[r][c] = wsf[OFF_MEAN0 + r * 32 + c] * scaleA;     // A = mean0/cN
    W2[r][c] = (r == c) ? 1.f : 0.f;
  }
  __syncthreads();
  LdsMat Y = W1, Z = W2, Ya = W0, Za = W4;
  ns_sqrt(Y, Z, Ya, Za, W3, lane);
  const float sq = sqrtf(cN), rs = rsqrtf(cN);
#pragma unroll
  for (int i = 0; i < 16; ++i) {
    int r = 16 * h + i;
    wsf[OFF_INVS0 + r * 32 + c] = Z[r][c] * rs;
    wsf[OFF_S0    + r * 32 + c] = Y[r][c] * sq;
  }
  // Chebyshev coefficients of log(t) on [CALPHA, CBETA]
  const float PIF = 3.14159265358979f;
  const float th = ((float)lane + 0.5f) * (PIF / 64.f);
  const float t  = 0.5f * (CALPHA + CBETA) + 0.5f * (CBETA - CALPHA) * cosf(th);
  const float fl = logf(t);
  for (int j = 0; j < NCHEB; ++j) {
    float v = fl * cosf((float)j * th) * (2.f / 64.f);
#pragma unroll
    for (int off = 32; off >= 1; off >>= 1) v += __shfl_xor(v, off);
    if (lane == 0) wsf[OFF_CHEB + j] = (j == 0) ? 0.5f * v : v;
  }
}

// Karcher step: accumulate sum_b log(inv_s0 x_b inv_s0)
extern "C" __global__ void __launch_bounds__(64)
spdbn_kB(const float* __restrict__ x, float* __restrict__ wsf) {
  __shared__ alignas(16) float M1[32][LDSW];
  __shared__ alignas(16) float M2[32][LDSW];
  const int lane = threadIdx.x, h = lane >> 5, c = lane & 31;
  ldmat(wsf + OFF_INVS0, M2, lane);
  const float* chg = wsf + OFF_CHEB;
  float Lb[16];
#pragma unroll
  for (int i = 0; i < 16; ++i) Lb[i] = 0.f;
  for (int b = blockIdx.x; b < BATCH; b += MAIN_BLOCKS) {
    ldmat(x + (size_t)b * 1024, M1, lane);
    __syncthreads();
    float tA[32], tOwn[16];
    whiten(M1, M2, lane, tA, tOwn);
    cheb_log_col<true>(M1, tA, tOwn, lane, chg, Lb);
    __syncthreads();
  }
#pragma unroll
  for (int i = 0; i < 16; ++i)
    atomicAdd(&wsf[OFF_LOGAVG + (16 * h + i) * 32 + c], Lb[i]);
}

// mean = s0 exp(log_avg) s0 ; inv_s = mean^{-1/2} ; s_sqrt = shift^{1/2}
extern "C" __global__ void __launch_bounds__(64)
spdbn_kS2(float* __restrict__ wsf, const float* __restrict__ shift) {
  __shared__ alignas(16) float W0[32][LDSW], W1[32][LDSW], W2[32][LDSW], W3[32][LDSW], W4[32][LDSW];
  const int lane = threadIdx.x, h = lane >> 5, c = lane & 31;
#pragma unroll
  for (int i = 0; i < 16; ++i) {
    int r = 16 * h + i;
    W0[r][c] = wsf[OFF_LOGAVG + r * 32 + c] * (1.f / (float)BATCH);   // LA
    W1[r][c] = (r == c) ? 1.f : 0.f;                                   // P = I
  }
  __syncthreads();
  for (int j = EXP_TERMS; j >= 1; --j) {                               // P = I + (LA/j)P
    mm64(W3, W0, W1, lane);
    const float inv = 1.f / (float)j;
#pragma unroll
    for (int i = 0; i < 16; ++i) {
      int r = 16 * h + i;
      W1[r][c] = ((r == c) ? 1.f : 0.f) + W3[r][c] * inv;
    }
    __syncthreads();
  }
#pragma unroll
  for (int i = 0; i < 16; ++i) { int r = 16 * h + i; W2[r][c] = wsf[OFF_S0 + r * 32 + c]; }
  __syncthreads();
  mm64(W3, W2, W1, lane);                                              // s0*E
  mm64(W0, W3, W2, lane);                                              // mean
  float tr = 0.f;
#pragma unroll
  for (int k = 0; k < 32; ++k) tr += W0[k][k];
  tr *= (1.f / 32.f);
  const float itr = 1.f / tr;
#pragma unroll
  for (int i = 0; i < 16; ++i) {
    int r = 16 * h + i;
    W1[r][c] = W0[r][c] * itr;
    W2[r][c] = (r == c) ? 1.f : 0.f;
  }
  __syncthreads();
  LdsMat Y = W1, Z = W2, Ya = W0, Za = W4;
  ns_sqrt(Y, Z, Ya, Za, W3, lane);
  const float rs = rsqrtf(tr);
#pragma unroll
  for (int i = 0; i < 16; ++i) { int r = 16 * h + i; wsf[OFF_INVS + r * 32 + c] = Z[r][c] * rs; }
  __syncthreads();
  // shift^{1/2}
  float tr2 = 0.f;
#pragma unroll
  for (int k = 0; k < 32; ++k) tr2 += shift[33 * k];
  tr2 *= (1.f / 32.f);
  const float itr2 = 1.f / tr2;
#pragma unroll
  for (int i = 0; i < 16; ++i) {
    int r = 16 * h + i;
    W1[r][c] = shift[r * 32 + c] * itr2;
    W2[r][c] = (r == c) ? 1.f : 0.f;
  }
  __syncthreads();
  LdsMat Y2 = W1, Z2 = W2, Ya2 = W0, Za2 = W4;
  ns_sqrt(Y2, Z2, Ya2, Za2, W3, lane);
  const float sq2 = sqrtf(tr2);
#pragma unroll
  for (int i = 0; i < 16; ++i) { int r = 16 * h + i; wsf[OFF_SSQRT + r * 32 + c] = Y2[r][c] * sq2; }
}

// BN whiten: L_b = log(inv_s x_b inv_s) -> d_out (scratch); var += ||L_b||_F^2
extern "C" __global__ void __launch_bounds__(64)
spdbn_kC(const float* __restrict__ x, float* __restrict__ wsf, float* __restrict__ outL) {
  __shared__ alignas(16) float M1[32][LDSW];
  __shared__ alignas(16) float M2[32][LDSW];
  const int lane = threadIdx.x, h = lane >> 5, c = lane & 31;
  ldmat(wsf + OFF_INVS, M2, lane);
  const float* chg = wsf + OFF_CHEB;
  float ss = 0.f;
  for (int b = blockIdx.x; b < BATCH; b += MAIN_BLOCKS) {
    ldmat(x + (size_t)b * 1024, M1, lane);
    __syncthreads();
    float tA[32], tOwn[16];
    whiten(M1, M2, lane, tA, tOwn);
    float Lh[16];
    cheb_log_col<false>(M1, tA, tOwn, lane, chg, Lh);
#pragma unroll
    for (int i = 0; i < 16; ++i) {
      outL[(size_t)b * 1024 + (16 * h + i) * 32 + c] = Lh[i];
      ss = fmaf(Lh[i], Lh[i], ss);
    }
    __syncthreads();
  }
#pragma unroll
  for (int off = 32; off >= 1; off >>= 1) ss += __shfl_xor(ss, off);
  if (lane == 0) atomicAdd(&wsf[OFF_VAR], ss);
}

extern "C" __global__ void spdbn_kS3(float* __restrict__ wsf, const float* __restrict__ scale) {
  if (threadIdx.x == 0) {
    float var = wsf[OFF_VAR] * (1.f / (float)BATCH);
    float stdv = sqrtf(var);
    wsf[OFF_P] = scale[0] / (stdv + 1e-5f);
  }
}

// out = s_sqrt * exp(p*L) * s_sqrt  (reads L from d_out, overwrites in place)
extern "C" __global__ void __launch_bounds__(64)
spdbn_kD(float* __restrict__ out, const float* __restrict__ wsf) {
  __shared__ alignas(16) float M1[32][LDSW];
  __shared__ alignas(16) float M2[32][LDSW];
  const int lane = threadIdx.x, h = lane >> 5, c = lane & 31;
  ldmat(wsf + OFF_SSQRT, M2, lane);
  const float p = wsf[OFF_P];
  for (int b = blockIdx.x; b < BATCH; b += MAIN_BLOCKS) {
#pragma unroll
    for (int e = 0; e < 4; ++e) {                       // M1 = p * L
      int idx = e * 256 + lane * 4;
      float4 v = *reinterpret_cast<const float4*>(out + (size_t)b * 1024 + idx);
      v.x *= p; v.y *= p; v.z *= p; v.w *= p;
      *reinterpret_cast<float4*>(&M1[idx >> 5][idx & 31]) = v;
    }
    __syncthreads();
    float Pf[32];                                       // P = I col c
#pragma unroll
    for (int k2 = 0; k2 < 32; ++k2) Pf[k2] = (k2 == c) ? 1.f : 0.f;
    for (int j = EXP_TERMS; j >= 1; --j) {              // P = I + (M/j)P, M = pL
      const float inv = 1.f / (float)j;
      float po[16];
#pragma unroll
      for (int i = 0; i < 16; ++i) {
        int r = 16 * h + i;
        po[i] = fmaf(dotrow36(&M1[r][0], Pf), inv, (r == c) ? 1.f : 0.f);
      }
      build_full(po, Pf, h);
    }
    __syncthreads();                                    // done reading M1 (pL)
#pragma unroll
    for (int i = 0; i < 16; ++i) M1[16 * h + i][c] = (h == 0) ? Pf[i] : Pf[16 + i];  // M1 = exp(pL)
    __syncthreads();
    float bcol[32];
#pragma unroll
    for (int j = 0; j < 8; ++j) {
      float4 v = *reinterpret_cast<const float4*>(&M2[c][4 * j]);   // Ssq col c
      bcol[4 * j + 0] = v.x; bcol[4 * j + 1] = v.y; bcol[4 * j + 2] = v.z; bcol[4 * j + 3] = v.w;
    }
    float vo[16];
#pragma unroll
    for (int i = 0; i < 16; ++i) vo[i] = dotrow36(&M1[16 * h + i][0], bcol);  // (P*Ssq)[r][c]
    float vf[32];
    build_full(vo, vf, h);
#pragma unroll
    for (int i = 0; i < 16; ++i) {
      int r = 16 * h + i;
      out[(size_t)b * 1024 + r * 32 + c] = dotrow36(&M2[r][0], vf);  // (Ssq*P*Ssq)[r][c]
    }
    __syncthreads();
  }
}

extern "C" void kernel_launch(void* const* d_in, const int* in_sizes, int n_in,
                              void* d_out, int out_size, void* d_ws, size_t ws_size,
                              hipStream_t stream) {
  const float* x     = (const float*)d_in[0];
  const float* shift = (const float*)d_in[1];
  const float* scale = (const float*)d_in[2];
  float* out = (float*)d_out;
  float* wsf = (float*)d_ws;

  size_t zbytes = 32768;
  if (ws_size < zbytes) zbytes = ws_size;
  hipMemsetAsync(d_ws, 0, zbytes, stream);

  hipLaunchKernelGGL(spdbn_kA,  dim3(4096), dim3(256), 0, stream, x, wsf);
  hipLaunchKernelGGL(spdbn_kS1, dim3(1),    dim3(64),  0, stream, wsf);
  hipLaunchKernelGGL(spdbn_kB,  dim3(MAIN_BLOCKS), dim3(64), 0, stream, x, wsf);
  hipLaunchKernelGGL(spdbn_kS2, dim3(1),    dim3(64),  0, stream, wsf, shift);
  hipLaunchKernelGGL(spdbn_kC,  dim3(MAIN_BLOCKS), dim3(64), 0, stream, x, wsf, out);
  hipLaunchKernelGGL(spdbn_kS3, dim3(1),    dim3(64),  0, stream, wsf, scale);
  hipLaunchKernelGGL(spdbn_kD,  dim3(MAIN_BLOCKS), dim3(64), 0, stream, out, wsf);
}

// Round 2
// 6494.745 us; speedup vs baseline: 5.1801x; 5.1801x over previous
//
#include <hip/hip_runtime.h>
#include <cstdint>
#include <cstddef>

#define BATCH       65536
#define LDSW        36          // padded LDS row stride for S-type matrices
#define NCHEB       26          // Chebyshev terms for log on [CALPHA, CBETA]
#define CALPHA      0.2f
#define CBETA       6.0f
#define NS_ITERS    6           // Newton-Schulz sqrt iterations
#define EXP_TERMS   12          // Taylor terms for matrix exp
#define MAIN_BLOCKS 4096        // main kernels: 4096 blocks x 64 threads (1 wave)

// ws float offsets
#define OFF_MEAN0   0
#define OFF_INVS0   1024
#define OFF_S0      2048
#define OFF_LOGAVG  3072
#define OFF_INVS    4096
#define OFF_SSQRT   5120
#define OFF_VAR     6144
#define OFF_P       6145
#define OFF_CHEB    6152        // 26 floats

typedef float (*LdsMat)[LDSW];

// ---------------- shared helpers ----------------

// Symmetric-matrix matvec, one wave = one matrix, lane = 32*h + c.
// o[i] = sum_k M[16h+i][k] * t[k]  computed as  sum_k M[k][16h+i] * t[k]
// (valid because M is symmetric). Row-slice reads M[k][16h..16h+15] are
// 2-address broadcasts (free); t read from LDS column tcol[k*TW] (conflict-free).
template <int W, int TW>
__device__ __forceinline__ void matvec_sym(const float (*M)[W], const float* tcol,
                                           int h, float* __restrict__ o) {
#pragma unroll
  for (int i = 0; i < 16; ++i) o[i] = 0.f;
#pragma unroll 2
  for (int k = 0; k < 32; ++k) {
    const float tk = tcol[k * TW];
    const float4* rp = reinterpret_cast<const float4*>(&M[k][16 * h]);
    float4 a0 = rp[0], a1 = rp[1], a2 = rp[2], a3 = rp[3];
    o[0]  = fmaf(a0.x, tk, o[0]);  o[1]  = fmaf(a0.y, tk, o[1]);
    o[2]  = fmaf(a0.z, tk, o[2]);  o[3]  = fmaf(a0.w, tk, o[3]);
    o[4]  = fmaf(a1.x, tk, o[4]);  o[5]  = fmaf(a1.y, tk, o[5]);
    o[6]  = fmaf(a1.z, tk, o[6]);  o[7]  = fmaf(a1.w, tk, o[7]);
    o[8]  = fmaf(a2.x, tk, o[8]);  o[9]  = fmaf(a2.y, tk, o[9]);
    o[10] = fmaf(a2.z, tk, o[10]); o[11] = fmaf(a2.w, tk, o[11]);
    o[12] = fmaf(a3.x, tk, o[12]); o[13] = fmaf(a3.y, tk, o[13]);
    o[14] = fmaf(a3.z, tk, o[14]); o[15] = fmaf(a3.w, tk, o[15]);
  }
}

// load row-major 32x32 global -> unpadded LDS [32][32]
__device__ __forceinline__ void ldmat_u(const float* __restrict__ g, float (*M)[32], int lane) {
#pragma unroll
  for (int e = 0; e < 4; ++e) {
    int idx = e * 256 + lane * 4;
    *reinterpret_cast<float4*>(&M[0][0] + idx) = *reinterpret_cast<const float4*>(g + idx);
  }
}

// load row-major 32x32 global -> padded LDS [32][LDSW]
__device__ __forceinline__ void ldmat_p(const float* __restrict__ g, float (*M)[LDSW], int lane) {
#pragma unroll
  for (int e = 0; e < 4; ++e) {
    int idx = e * 256 + lane * 4;
    *reinterpret_cast<float4*>(&M[idx >> 5][idx & 31]) = *reinterpret_cast<const float4*>(g + idx);
  }
}

// M1 = x (symmetric, in). Computes Ytilde = g*(S x S) - m*I into M1 (overwrites x).
// tOwn[i] = Ytilde[16h+i][c]. Uses Tb as scratch column buffer.
__device__ __forceinline__ void whiten_core(float (*M1)[32], const float (*M2)[LDSW],
                                            float (*Tb)[32], int lane, float* tOwn) {
  const int h = lane >> 5, c = lane & 31;
  float uo[16];
  matvec_sym<32, LDSW>(M1, &M2[0][c], h, uo);      // u = x * S[:,c]
#pragma unroll
  for (int i = 0; i < 16; ++i) Tb[16 * h + i][c] = uo[i];
  __syncthreads();
  float yo[16];
  matvec_sym<LDSW, 32>(M2, &Tb[0][c], h, yo);      // y = S * u
  const float g  = 2.f / (CBETA - CALPHA);
  const float mm = (CALPHA + CBETA) / (CBETA - CALPHA);
  __syncthreads();                                 // all x-reads of M1 done before overwrite
#pragma unroll
  for (int i = 0; i < 16; ++i) {
    int r = 16 * h + i;
    tOwn[i] = fmaf(yo[i], g, (r == c) ? -mm : 0.f);
    M1[r][c] = tOwn[i];
  }
  __syncthreads();
}

// Chebyshev log of Ytilde (in M1, symmetric). Lout accumulates (ACCUM) or is set.
template <bool ACCUM>
__device__ __forceinline__ void cheb_core(const float (*M1)[32], float (*Tb)[32],
                                          const float* chS, int lane,
                                          const float* tOwn, float* Lout) {
  const int h = lane >> 5, c = lane & 31;
  float pOwn[16], tprev[16];
  const float c0 = chS[0], c1 = chS[1];
#pragma unroll
  for (int i = 0; i < 16; ++i) {
    int r = 16 * h + i;
    float t0 = (r == c) ? 1.f : 0.f;
    pOwn[i]  = t0;
    tprev[i] = tOwn[i];
    float val = fmaf(c1, tOwn[i], c0 * t0);
    if (ACCUM) Lout[i] += val; else Lout[i] = val;
  }
  // k = 2: T1 column read directly from M1 (Ytilde symmetric)
  {
    float s[16];
    matvec_sym<32, 32>(M1, &M1[0][c], h, s);
    const float ck = chS[2];
#pragma unroll
    for (int i = 0; i < 16; ++i) {
      float tn = fmaf(2.f, s[i], -pOwn[i]);
      Lout[i]  = fmaf(ck, tn, Lout[i]);
      pOwn[i]  = tprev[i];
      tprev[i] = tn;
      Tb[16 * h + i][c] = tn;
    }
    __syncthreads();
  }
  for (int k = 3; k < NCHEB; ++k) {
    float s[16];
    matvec_sym<32, 32>(M1, &Tb[0][c], h, s);
    const float ck = chS[k];
    float tn[16];
#pragma unroll
    for (int i = 0; i < 16; ++i) {
      tn[i]   = fmaf(2.f, s[i], -pOwn[i]);
      Lout[i] = fmaf(ck, tn[i], Lout[i]);
    }
#pragma unroll
    for (int i = 0; i < 16; ++i) {
      Tb[16 * h + i][c] = tn[i];
      pOwn[i]  = tprev[i];
      tprev[i] = tn[i];
    }
    __syncthreads();
  }
}

// ---------- tiny-kernel helpers (single block, 64 threads) ----------

__device__ __forceinline__ float dotrow36(const float* Arow, const float* v) {
  float s = 0.f;
#pragma unroll
  for (int j = 0; j < 8; ++j) {
    float4 a = *reinterpret_cast<const float4*>(Arow + 4 * j);
    s = fmaf(a.x, v[4 * j + 0], s);
    s = fmaf(a.y, v[4 * j + 1], s);
    s = fmaf(a.z, v[4 * j + 2], s);
    s = fmaf(a.w, v[4 * j + 3], s);
  }
  return s;
}

__device__ void mm64(float (*D)[LDSW], const float (*A)[LDSW], const float (*Bm)[LDSW], int lane) {
  const int h = lane >> 5, c = lane & 31;
  float bcol[32];
#pragma unroll
  for (int k = 0; k < 32; ++k) bcol[k] = Bm[k][c];
  float o[16];
#pragma unroll
  for (int i = 0; i < 16; ++i) o[i] = dotrow36(&A[16 * h + i][0], bcol);
  __syncthreads();
#pragma unroll
  for (int i = 0; i < 16; ++i) D[16 * h + i][c] = o[i];
  __syncthreads();
}

// coupled Newton-Schulz: Y->A^(1/2), Z->A^(-1/2); A=Y initially (spec near 1)
__device__ void ns_sqrt(LdsMat& Y, LdsMat& Z, LdsMat& Ya, LdsMat& Za, LdsMat T, int lane) {
  const int h = lane >> 5, c = lane & 31;
  for (int it = 0; it < NS_ITERS; ++it) {
    mm64(T, Z, Y, lane);                      // T = Z*Y
#pragma unroll
    for (int i = 0; i < 16; ++i) {
      int r = 16 * h + i;
      T[r][c] = ((r == c) ? 1.5f : 0.f) - 0.5f * T[r][c];
    }
    __syncthreads();
    mm64(Ya, Y, T, lane);                     // Y' = Y*T
    mm64(Za, T, Z, lane);                     // Z' = T*Z
    LdsMat t1 = Y; Y = Ya; Ya = t1;
    LdsMat t2 = Z; Z = Za; Za = t2;
  }
}

// ---------- kernels ----------

// mean over batch -> ws[OFF_MEAN0] (raw sum; divided later)
extern "C" __global__ void __launch_bounds__(256)
spdbn_kA(const float* __restrict__ x, float* __restrict__ wsf) {
  const int e  = (blockIdx.x & 3) * 256 + threadIdx.x;   // matrix entry 0..1023
  const int bs = blockIdx.x >> 2;                        // 0..1023
  float acc = 0.f;
  for (int t = 0; t < 64; ++t)
    acc += x[(size_t)(bs + 1024 * t) * 1024 + e];
  atomicAdd(&wsf[OFF_MEAN0 + e], acc);
}

// mean0^{±1/2} via Newton-Schulz; Chebyshev coefficients of log via 64-pt quadrature
extern "C" __global__ void __launch_bounds__(64)
spdbn_kS1(float* __restrict__ wsf) {
  __shared__ alignas(16) float W0[32][LDSW], W1[32][LDSW], W2[32][LDSW], W3[32][LDSW], W4[32][LDSW];
  const int lane = threadIdx.x, h = lane >> 5, c = lane & 31;
  float sacc = 0.f;
#pragma unroll
  for (int k = 0; k < 32; ++k) sacc += wsf[OFF_MEAN0 + 33 * k];
  const float cN = sacc / (32.f * (float)BATCH);         // trace(mean0)/32
  const float scaleA = 32.f / sacc;                      // 1/(B*cN)
#pragma unroll
  for (int i = 0; i < 16; ++i) {
    int r = 16 * h + i;
    W1[r][c] = wsf[OFF_MEAN0 + r * 32 + c] * scaleA;     // A = mean0/cN
    W2[r][c] = (r == c) ? 1.f : 0.f;
  }
  __syncthreads();
  LdsMat Y = W1, Z = W2, Ya = W0, Za = W4;
  ns_sqrt(Y, Z, Ya, Za, W3, lane);
  const float sq = sqrtf(cN), rs = rsqrtf(cN);
#pragma unroll
  for (int i = 0; i < 16; ++i) {
    int r = 16 * h + i;
    wsf[OFF_INVS0 + r * 32 + c] = Z[r][c] * rs;
    wsf[OFF_S0    + r * 32 + c] = Y[r][c] * sq;
  }
  // Chebyshev coefficients of log(t) on [CALPHA, CBETA]
  const float PIF = 3.14159265358979f;
  const float th = ((float)lane + 0.5f) * (PIF / 64.f);
  const float t  = 0.5f * (CALPHA + CBETA) + 0.5f * (CBETA - CALPHA) * cosf(th);
  const float fl = logf(t);
  for (int j = 0; j < NCHEB; ++j) {
    float v = fl * cosf((float)j * th) * (2.f / 64.f);
#pragma unroll
    for (int off = 32; off >= 1; off >>= 1) v += __shfl_xor(v, off);
    if (lane == 0) wsf[OFF_CHEB + j] = (j == 0) ? 0.5f * v : v;
  }
}

// Karcher step: accumulate sum_b log(inv_s0 x_b inv_s0)
extern "C" __global__ void __launch_bounds__(64, 3)
spdbn_kB(const float* __restrict__ x, float* __restrict__ wsf) {
  __shared__ alignas(16) float M1[32][32];
  __shared__ alignas(16) float M2[32][LDSW];
  __shared__ alignas(16) float Tb[32][32];
  __shared__ float chS[NCHEB];
  const int lane = threadIdx.x, h = lane >> 5, c = lane & 31;
  ldmat_p(wsf + OFF_INVS0, M2, lane);
  if (lane < NCHEB) chS[lane] = wsf[OFF_CHEB + lane];
  __syncthreads();
  float Lb[16];
#pragma unroll
  for (int i = 0; i < 16; ++i) Lb[i] = 0.f;
  for (int b = blockIdx.x; b < BATCH; b += MAIN_BLOCKS) {
    ldmat_u(x + (size_t)b * 1024, M1, lane);
    __syncthreads();
    float tOwn[16];
    whiten_core(M1, M2, Tb, lane, tOwn);
    cheb_core<true>(M1, Tb, chS, lane, tOwn, Lb);
    __syncthreads();
  }
#pragma unroll
  for (int i = 0; i < 16; ++i)
    atomicAdd(&wsf[OFF_LOGAVG + (16 * h + i) * 32 + c], Lb[i]);
}

// mean = s0 exp(log_avg) s0 ; inv_s = mean^{-1/2} ; s_sqrt = shift^{1/2}
extern "C" __global__ void __launch_bounds__(64)
spdbn_kS2(float* __restrict__ wsf, const float* __restrict__ shift) {
  __shared__ alignas(16) float W0[32][LDSW], W1[32][LDSW], W2[32][LDSW], W3[32][LDSW], W4[32][LDSW];
  const int lane = threadIdx.x, h = lane >> 5, c = lane & 31;
#pragma unroll
  for (int i = 0; i < 16; ++i) {
    int r = 16 * h + i;
    W0[r][c] = wsf[OFF_LOGAVG + r * 32 + c] * (1.f / (float)BATCH);   // LA
    W1[r][c] = (r == c) ? 1.f : 0.f;                                   // P = I
  }
  __syncthreads();
  for (int j = EXP_TERMS; j >= 1; --j) {                               // P = I + (LA/j)P
    mm64(W3, W0, W1, lane);
    const float inv = 1.f / (float)j;
#pragma unroll
    for (int i = 0; i < 16; ++i) {
      int r = 16 * h + i;
      W1[r][c] = ((r == c) ? 1.f : 0.f) + W3[r][c] * inv;
    }
    __syncthreads();
  }
#pragma unroll
  for (int i = 0; i < 16; ++i) { int r = 16 * h + i; W2[r][c] = wsf[OFF_S0 + r * 32 + c]; }
  __syncthreads();
  mm64(W3, W2, W1, lane);                                              // s0*E
  mm64(W0, W3, W2, lane);                                              // mean
  float tr = 0.f;
#pragma unroll
  for (int k = 0; k < 32; ++k) tr += W0[k][k];
  tr *= (1.f / 32.f);
  const float itr = 1.f / tr;
#pragma unroll
  for (int i = 0; i < 16; ++i) {
    int r = 16 * h + i;
    W1[r][c] = W0[r][c] * itr;
    W2[r][c] = (r == c) ? 1.f : 0.f;
  }
  __syncthreads();
  LdsMat Y = W1, Z = W2, Ya = W0, Za = W4;
  ns_sqrt(Y, Z, Ya, Za, W3, lane);
  const float rs = rsqrtf(tr);
#pragma unroll
  for (int i = 0; i < 16; ++i) { int r = 16 * h + i; wsf[OFF_INVS + r * 32 + c] = Z[r][c] * rs; }
  __syncthreads();
  // shift^{1/2}
  float tr2 = 0.f;
#pragma unroll
  for (int k = 0; k < 32; ++k) tr2 += shift[33 * k];
  tr2 *= (1.f / 32.f);
  const float itr2 = 1.f / tr2;
#pragma unroll
  for (int i = 0; i < 16; ++i) {
    int r = 16 * h + i;
    W1[r][c] = shift[r * 32 + c] * itr2;
    W2[r][c] = (r == c) ? 1.f : 0.f;
  }
  __syncthreads();
  LdsMat Y2 = W1, Z2 = W2, Ya2 = W0, Za2 = W4;
  ns_sqrt(Y2, Z2, Ya2, Za2, W3, lane);
  const float sq2 = sqrtf(tr2);
#pragma unroll
  for (int i = 0; i < 16; ++i) { int r = 16 * h + i; wsf[OFF_SSQRT + r * 32 + c] = Y2[r][c] * sq2; }
}

// BN whiten: L_b = log(inv_s x_b inv_s) -> d_out (scratch); var += ||L_b||_F^2
extern "C" __global__ void __launch_bounds__(64, 3)
spdbn_kC(const float* __restrict__ x, float* __restrict__ wsf, float* __restrict__ outL) {
  __shared__ alignas(16) float M1[32][32];
  __shared__ alignas(16) float M2[32][LDSW];
  __shared__ alignas(16) float Tb[32][32];
  __shared__ float chS[NCHEB];
  const int lane = threadIdx.x, h = lane >> 5, c = lane & 31;
  ldmat_p(wsf + OFF_INVS, M2, lane);
  if (lane < NCHEB) chS[lane] = wsf[OFF_CHEB + lane];
  __syncthreads();
  float ss = 0.f;
  for (int b = blockIdx.x; b < BATCH; b += MAIN_BLOCKS) {
    ldmat_u(x + (size_t)b * 1024, M1, lane);
    __syncthreads();
    float tOwn[16];
    whiten_core(M1, M2, Tb, lane, tOwn);
    float Lh[16];
    cheb_core<false>(M1, Tb, chS, lane, tOwn, Lh);
#pragma unroll
    for (int i = 0; i < 16; ++i) {
      outL[(size_t)b * 1024 + (16 * h + i) * 32 + c] = Lh[i];
      ss = fmaf(Lh[i], Lh[i], ss);
    }
    __syncthreads();
  }
#pragma unroll
  for (int off = 32; off >= 1; off >>= 1) ss += __shfl_xor(ss, off);
  if (lane == 0) atomicAdd(&wsf[OFF_VAR], ss);
}

extern "C" __global__ void spdbn_kS3(float* __restrict__ wsf, const float* __restrict__ scale) {
  if (threadIdx.x == 0) {
    float var = wsf[OFF_VAR] * (1.f / (float)BATCH);
    float stdv = sqrtf(var);
    wsf[OFF_P] = scale[0] / (stdv + 1e-5f);
  }
}

// out = s_sqrt * exp(p*L) * s_sqrt  (reads L from d_out, overwrites in place)
extern "C" __global__ void __launch_bounds__(64, 3)
spdbn_kD(float* __restrict__ out, const float* __restrict__ wsf) {
  __shared__ alignas(16) float M1[32][32];   // p*L (symmetric)
  __shared__ alignas(16) float Pb[32][32];   // exp polynomial (symmetric)
  __shared__ alignas(16) float Tb[32][32];   // column scratch
  __shared__ alignas(16) float M2[32][LDSW]; // s_sqrt (padded)
  const int lane = threadIdx.x, h = lane >> 5, c = lane & 31;
  ldmat_p(wsf + OFF_SSQRT, M2, lane);
  const float p = wsf[OFF_P];
  __syncthreads();
  for (int b = blockIdx.x; b < BATCH; b += MAIN_BLOCKS) {
#pragma unroll
    for (int e = 0; e < 4; ++e) {                       // M1 = p * L
      int idx = e * 256 + lane * 4;
      float4 v = *reinterpret_cast<const float4*>(out + (size_t)b * 1024 + idx);
      v.x *= p; v.y *= p; v.z *= p; v.w *= p;
      *reinterpret_cast<float4*>(&M1[0][0] + idx) = v;
    }
#pragma unroll
    for (int i = 0; i < 16; ++i) {                      // Pb = I
      int r = 16 * h + i;
      Pb[r][c] = (r == c) ? 1.f : 0.f;
    }
    __syncthreads();
    for (int j = EXP_TERMS; j >= 1; --j) {              // P = I + (M/j)P, M = pL
      float po[16];
      matvec_sym<32, 32>(M1, &Pb[0][c], h, po);
      const float inv = 1.f / (float)j;
      __syncthreads();
#pragma unroll
      for (int i = 0; i < 16; ++i) {
        int r = 16 * h + i;
        Pb[r][c] = fmaf(po[i], inv, (r == c) ? 1.f : 0.f);
      }
      __syncthreads();
    }
    // v = P * Ssq[:,c]   (P symmetric)
    float vo[16];
    matvec_sym<32, LDSW>(Pb, &M2[0][c], h, vo);
#pragma unroll
    for (int i = 0; i < 16; ++i) Tb[16 * h + i][c] = vo[i];
    __syncthreads();
    // out[:,c] = Ssq * v
    float o2[16];
    matvec_sym<LDSW, 32>(M2, &Tb[0][c], h, o2);
#pragma unroll
    for (int i = 0; i < 16; ++i)
      out[(size_t)b * 1024 + (16 * h + i) * 32 + c] = o2[i];
    __syncthreads();
  }
}

extern "C" void kernel_launch(void* const* d_in, const int* in_sizes, int n_in,
                              void* d_out, int out_size, void* d_ws, size_t ws_size,
                              hipStream_t stream) {
  const float* x     = (const float*)d_in[0];
  const float* shift = (const float*)d_in[1];
  const float* scale = (const float*)d_in[2];
  float* out = (float*)d_out;
  float* wsf = (float*)d_ws;

  size_t zbytes = 32768;
  if (ws_size < zbytes) zbytes = ws_size;
  hipMemsetAsync(d_ws, 0, zbytes, stream);

  hipLaunchKernelGGL(spdbn_kA,  dim3(4096), dim3(256), 0, stream, x, wsf);
  hipLaunchKernelGGL(spdbn_kS1, dim3(1),    dim3(64),  0, stream, wsf);
  hipLaunchKernelGGL(spdbn_kB,  dim3(MAIN_BLOCKS), dim3(64), 0, stream, x, wsf);
  hipLaunchKernelGGL(spdbn_kS2, dim3(1),    dim3(64),  0, stream, wsf, shift);
  hipLaunchKernelGGL(spdbn_kC,  dim3(MAIN_BLOCKS), dim3(64), 0, stream, x, wsf, out);
  hipLaunchKernelGGL(spdbn_kS3, dim3(1),    dim3(64),  0, stream, wsf, scale);
  hipLaunchKernelGGL(spdbn_kD,  dim3(MAIN_BLOCKS), dim3(64), 0, stream, out, wsf);
}

// Round 3
// 1834.447 us; speedup vs baseline: 18.3397x; 3.5404x over previous
//
#include <hip/hip_runtime.h>
#include <cstdint>
#include <cstddef>

#define BATCH       65536
#define LDSW        36          // padded LDS row stride for tiny-kernel matrices
#define NCHEB       26          // Chebyshev terms for log on [CALPHA, CBETA]
#define CALPHA      0.2f
#define CBETA       6.0f
#define NS_ITERS    6           // Newton-Schulz sqrt iterations
#define EXP_TERMS   12          // Taylor terms for matrix exp
#define MAIN_BLOCKS 3072        // main kernels: 3072 1-wave blocks (12/CU co-resident)

// ws float offsets
#define OFF_MEAN0   0
#define OFF_INVS0   1024
#define OFF_S0      2048
#define OFF_LOGAVG  3072
#define OFF_INVS    4096
#define OFF_SSQRT   5120
#define OFF_VAR     6144
#define OFF_P       6145
#define OFF_CHEB    6152        // 26 floats

typedef float (*LdsMat)[LDSW];
typedef __attribute__((ext_vector_type(8))) short          short8;
typedef __attribute__((ext_vector_type(4))) float          f32x4;
typedef __attribute__((ext_vector_type(4))) unsigned short us4;
typedef unsigned short u16t;

#define MFMA16(a, b, c) __builtin_amdgcn_mfma_f32_16x16x32_bf16((a), (b), (c), 0, 0, 0)

// ---------------- split-bf16 helpers ----------------
// a ~= hi + lo, both bf16 (round-to-nearest-ish via +0x8000 bit trick).
__device__ __forceinline__ void splitf(float a, u16t& h, u16t& l) {
  unsigned u  = __float_as_uint(a);
  unsigned uh = (u + 0x8000u) & 0xFFFF0000u;
  float    r  = a - __uint_as_float(uh);
  unsigned ul = __float_as_uint(r) + 0x8000u;
  h = (u16t)(uh >> 16);
  l = (u16t)(ul >> 16);
}

// Fragment read: for symmetric (or col-major-staged) matrix array G[32][40],
// tile index t, returns 8 contiguous bf16 along K at row 16t+c15, k0=8g.
__device__ __forceinline__ short8 fragr(const u16t (*G)[40], int t, int c15, int g) {
  return *reinterpret_cast<const short8*>(&G[16 * t + c15][8 * g]);
}

// Stage one C-layout tile (4 f32, rows 16i+4g+0..3, col 16j+c15) into
// col-major hi/lo arrays: G[col][row..row+3] — a single b64 write each.
__device__ __forceinline__ void stage4(u16t (*Gh)[40], u16t (*Gl)[40],
                                       int i, int j, int g, int c15, f32x4 v) {
  us4 hv, lv;
#pragma unroll
  for (int r = 0; r < 4; ++r) { u16t h, l; splitf(v[r], h, l); hv[r] = h; lv[r] = l; }
  *reinterpret_cast<us4*>(&Gh[16 * j + c15][16 * i + 4 * g]) = hv;
  *reinterpret_cast<us4*>(&Gl[16 * j + c15][16 * i + 4 * g]) = lv;
}

// Load hi/lo fragments of a symmetric 32x32 f32 matrix from global (ws).
// Same frags serve A-role (row=16t+c15) and B-role (col=16t+c15) by symmetry.
__device__ __forceinline__ void load_sym_frags(const float* base, int c15, int g,
                                               short8* Fh, short8* Fl) {
#pragma unroll
  for (int t = 0; t < 2; ++t) {
    const float* sp = base + (16 * t + c15) * 32 + 8 * g;
    short8 hh, ll;
#pragma unroll
    for (int j = 0; j < 8; ++j) {
      u16t h, l;
      splitf(sp[j], h, l);
      hh[j] = (short)h;
      ll[j] = (short)l;
    }
    Fh[t] = hh;
    Fl[t] = ll;
  }
}

// ---------------- MFMA whiten + Chebyshev-log core ----------------
// Computes L = cheb_log( g*(S x S) - m*I ) for one matrix; L in C-layout regs.
// ACCUM: L += (kB batch-sum) vs L = (kC per-matrix).
template <bool ACCUM>
__device__ __forceinline__ void whiten_cheb(
    const float* __restrict__ xb, const short8* S_h, const short8* S_l,
    u16t (*A0h)[40], u16t (*A0l)[40], u16t (*A1h)[40], u16t (*A1l)[40],
    const float* chS, int g, int c15, f32x4 (&L)[2][2]) {
  const f32x4 z4 = {0.f, 0.f, 0.f, 0.f};
  const int lane = 16 * g + c15;
  // 1. stage X (symmetric) hi/lo into A0
#pragma unroll
  for (int e = 0; e < 4; ++e) {
    int idx = e * 256 + lane * 4;
    float4 v = *reinterpret_cast<const float4*>(xb + idx);
    int row = idx >> 5, col = idx & 31;
    us4 hv, lv; u16t h, l;
    splitf(v.x, h, l); hv[0] = h; lv[0] = l;
    splitf(v.y, h, l); hv[1] = h; lv[1] = l;
    splitf(v.z, h, l); hv[2] = h; lv[2] = l;
    splitf(v.w, h, l); hv[3] = h; lv[3] = l;
    *reinterpret_cast<us4*>(&A0h[row][col]) = hv;
    *reinterpret_cast<us4*>(&A0l[row][col]) = lv;
  }
  __syncthreads();
  // 2. V2 = X * S   (A = X from LDS via symmetry, B = S regs)
  f32x4 acc[2][2];
#pragma unroll
  for (int i = 0; i < 2; ++i) {
    short8 Xh = fragr(A0h, i, c15, g), Xl = fragr(A0l, i, c15, g);
#pragma unroll
    for (int j = 0; j < 2; ++j) {
      f32x4 a = z4;
      a = MFMA16(Xl, S_h[j], a);
      a = MFMA16(Xh, S_l[j], a);
      a = MFMA16(Xh, S_h[j], a);
      acc[i][j] = a;
    }
  }
  __syncthreads();
#pragma unroll
  for (int i = 0; i < 2; ++i)
#pragma unroll
    for (int j = 0; j < 2; ++j) stage4(A1h, A1l, i, j, g, c15, acc[i][j]);  // col-major
  __syncthreads();
  // 3. Y = S * V2 → Ytilde = GSC*Y - MSH*I
#pragma unroll
  for (int j = 0; j < 2; ++j) {
    short8 Bh = fragr(A1h, j, c15, g), Bl = fragr(A1l, j, c15, g);
#pragma unroll
    for (int i = 0; i < 2; ++i) {
      f32x4 a = z4;
      a = MFMA16(S_l[i], Bh, a);
      a = MFMA16(S_h[i], Bl, a);
      a = MFMA16(S_h[i], Bh, a);
      acc[i][j] = a;
    }
  }
  const float GSC = 2.f / (CBETA - CALPHA);
  const float MSH = (CALPHA + CBETA) / (CBETA - CALPHA);
  const float c0 = chS[0], c1 = chS[1];
  f32x4 Tm1[2][2], Tm2[2][2];
#pragma unroll
  for (int i = 0; i < 2; ++i)
#pragma unroll
    for (int j = 0; j < 2; ++j)
#pragma unroll
      for (int r = 0; r < 4; ++r) {
        bool dg = (16 * i + 4 * g + r) == (16 * j + c15);
        float yt = fmaf(acc[i][j][r], GSC, dg ? -MSH : 0.f);
        Tm1[i][j][r] = yt;                       // T1
        Tm2[i][j][r] = dg ? 1.f : 0.f;           // T0
        float t0 = fmaf(c1, yt, dg ? c0 : 0.f);  // c0*T0 + c1*T1
        if (ACCUM) L[i][j][r] += t0; else L[i][j][r] = t0;
      }
  __syncthreads();
#pragma unroll
  for (int i = 0; i < 2; ++i)
#pragma unroll
    for (int j = 0; j < 2; ++j) stage4(A0h, A0l, i, j, g, c15, Tm1[i][j]);  // Ytilde
  __syncthreads();
  // Ytilde A-frags hoisted for the whole recurrence; T1 B-frags == same frags
  short8 Ya_h[2], Ya_l[2], Bh[2], Bl[2];
#pragma unroll
  for (int t = 0; t < 2; ++t) {
    Ya_h[t] = fragr(A0h, t, c15, g);
    Ya_l[t] = fragr(A0l, t, c15, g);
    Bh[t] = Ya_h[t];
    Bl[t] = Ya_l[t];
  }
  // 4. T_k = 2*Ytilde*T_{k-1} - T_{k-2}; L += c_k T_k
  for (int k = 2; k < NCHEB; ++k) {
    const float ck = chS[k];
#pragma unroll
    for (int i = 0; i < 2; ++i)
#pragma unroll
      for (int j = 0; j < 2; ++j) {
        f32x4 a = z4;
        a = MFMA16(Ya_l[i], Bh[j], a);
        a = MFMA16(Ya_h[i], Bl[j], a);
        a = MFMA16(Ya_h[i], Bh[j], a);
        acc[i][j] = a;
      }
#pragma unroll
    for (int i = 0; i < 2; ++i)
#pragma unroll
      for (int j = 0; j < 2; ++j)
#pragma unroll
        for (int r = 0; r < 4; ++r) {
          float tk = fmaf(2.f, acc[i][j][r], -Tm2[i][j][r]);
          L[i][j][r]   = fmaf(ck, tk, L[i][j][r]);
          Tm2[i][j][r] = Tm1[i][j][r];
          Tm1[i][j][r] = tk;
        }
    if (k < NCHEB - 1) {
      u16t (*Wh)[40] = (k & 1) ? A0h : A1h;
      u16t (*Wl)[40] = (k & 1) ? A0l : A1l;
      __syncthreads();
#pragma unroll
      for (int i = 0; i < 2; ++i)
#pragma unroll
        for (int j = 0; j < 2; ++j) stage4(Wh, Wl, i, j, g, c15, Tm1[i][j]);
      __syncthreads();
#pragma unroll
      for (int t = 0; t < 2; ++t) { Bh[t] = fragr(Wh, t, c15, g); Bl[t] = fragr(Wl, t, c15, g); }
    }
  }
}

// ---------- tiny-kernel helpers (single block, 64 threads; unchanged) ----------

__device__ __forceinline__ float dotrow36(const float* Arow, const float* v) {
  float s = 0.f;
#pragma unroll
  for (int j = 0; j < 8; ++j) {
    float4 a = *reinterpret_cast<const float4*>(Arow + 4 * j);
    s = fmaf(a.x, v[4 * j + 0], s);
    s = fmaf(a.y, v[4 * j + 1], s);
    s = fmaf(a.z, v[4 * j + 2], s);
    s = fmaf(a.w, v[4 * j + 3], s);
  }
  return s;
}

__device__ void mm64(float (*D)[LDSW], const float (*A)[LDSW], const float (*Bm)[LDSW], int lane) {
  const int h = lane >> 5, c = lane & 31;
  float bcol[32];
#pragma unroll
  for (int k = 0; k < 32; ++k) bcol[k] = Bm[k][c];
  float o[16];
#pragma unroll
  for (int i = 0; i < 16; ++i) o[i] = dotrow36(&A[16 * h + i][0], bcol);
  __syncthreads();
#pragma unroll
  for (int i = 0; i < 16; ++i) D[16 * h + i][c] = o[i];
  __syncthreads();
}

__device__ void ns_sqrt(LdsMat& Y, LdsMat& Z, LdsMat& Ya, LdsMat& Za, LdsMat T, int lane) {
  const int h = lane >> 5, c = lane & 31;
  for (int it = 0; it < NS_ITERS; ++it) {
    mm64(T, Z, Y, lane);
#pragma unroll
    for (int i = 0; i < 16; ++i) {
      int r = 16 * h + i;
      T[r][c] = ((r == c) ? 1.5f : 0.f) - 0.5f * T[r][c];
    }
    __syncthreads();
    mm64(Ya, Y, T, lane);
    mm64(Za, T, Z, lane);
    LdsMat t1 = Y; Y = Ya; Ya = t1;
    LdsMat t2 = Z; Z = Za; Za = t2;
  }
}

// ---------- kernels ----------

extern "C" __global__ void __launch_bounds__(256)
spdbn_kA(const float* __restrict__ x, float* __restrict__ wsf) {
  const int e  = (blockIdx.x & 3) * 256 + threadIdx.x;
  const int bs = blockIdx.x >> 2;
  float acc = 0.f;
  for (int t = 0; t < 64; ++t)
    acc += x[(size_t)(bs + 1024 * t) * 1024 + e];
  atomicAdd(&wsf[OFF_MEAN0 + e], acc);
}

extern "C" __global__ void __launch_bounds__(64)
spdbn_kS1(float* __restrict__ wsf) {
  __shared__ alignas(16) float W0[32][LDSW], W1[32][LDSW], W2[32][LDSW], W3[32][LDSW], W4[32][LDSW];
  const int lane = threadIdx.x, h = lane >> 5, c = lane & 31;
  float sacc = 0.f;
#pragma unroll
  for (int k = 0; k < 32; ++k) sacc += wsf[OFF_MEAN0 + 33 * k];
  const float cN = sacc / (32.f * (float)BATCH);
  const float scaleA = 32.f / sacc;
#pragma unroll
  for (int i = 0; i < 16; ++i) {
    int r = 16 * h + i;
    W1[r][c] = wsf[OFF_MEAN0 + r * 32 + c] * scaleA;
    W2[r][c] = (r == c) ? 1.f : 0.f;
  }
  __syncthreads();
  LdsMat Y = W1, Z = W2, Ya = W0, Za = W4;
  ns_sqrt(Y, Z, Ya, Za, W3, lane);
  const float sq = sqrtf(cN), rs = rsqrtf(cN);
#pragma unroll
  for (int i = 0; i < 16; ++i) {
    int r = 16 * h + i;
    wsf[OFF_INVS0 + r * 32 + c] = Z[r][c] * rs;
    wsf[OFF_S0    + r * 32 + c] = Y[r][c] * sq;
  }
  const float PIF = 3.14159265358979f;
  const float th = ((float)lane + 0.5f) * (PIF / 64.f);
  const float t  = 0.5f * (CALPHA + CBETA) + 0.5f * (CBETA - CALPHA) * cosf(th);
  const float fl = logf(t);
  for (int j = 0; j < NCHEB; ++j) {
    float v = fl * cosf((float)j * th) * (2.f / 64.f);
#pragma unroll
    for (int off = 32; off >= 1; off >>= 1) v += __shfl_xor(v, off);
    if (lane == 0) wsf[OFF_CHEB + j] = (j == 0) ? 0.5f * v : v;
  }
}

// Karcher step: accumulate sum_b log(inv_s0 x_b inv_s0)
extern "C" __global__ void __launch_bounds__(64, 3)
spdbn_kB(const float* __restrict__ x, float* __restrict__ wsf) {
  __shared__ alignas(16) u16t A0h[32][40], A0l[32][40], A1h[32][40], A1l[32][40];
  __shared__ float chS[NCHEB];
  const int lane = threadIdx.x;
  const int g = lane >> 4, c15 = lane & 15;
  if (lane < NCHEB) chS[lane] = wsf[OFF_CHEB + lane];
  short8 S_h[2], S_l[2];
  load_sym_frags(wsf + OFF_INVS0, c15, g, S_h, S_l);
  const f32x4 z4 = {0.f, 0.f, 0.f, 0.f};
  f32x4 L[2][2];
#pragma unroll
  for (int i = 0; i < 2; ++i)
#pragma unroll
    for (int j = 0; j < 2; ++j) L[i][j] = z4;
  __syncthreads();
  for (int b = blockIdx.x; b < BATCH; b += MAIN_BLOCKS) {
    whiten_cheb<true>(x + (size_t)b * 1024, S_h, S_l, A0h, A0l, A1h, A1l, chS, g, c15, L);
    __syncthreads();
  }
#pragma unroll
  for (int i = 0; i < 2; ++i)
#pragma unroll
    for (int j = 0; j < 2; ++j)
#pragma unroll
      for (int r = 0; r < 4; ++r)
        atomicAdd(&wsf[OFF_LOGAVG + (16 * i + 4 * g + r) * 32 + 16 * j + c15], L[i][j][r]);
}

extern "C" __global__ void __launch_bounds__(64)
spdbn_kS2(float* __restrict__ wsf, const float* __restrict__ shift) {
  __shared__ alignas(16) float W0[32][LDSW], W1[32][LDSW], W2[32][LDSW], W3[32][LDSW], W4[32][LDSW];
  const int lane = threadIdx.x, h = lane >> 5, c = lane & 31;
#pragma unroll
  for (int i = 0; i < 16; ++i) {
    int r = 16 * h + i;
    W0[r][c] = wsf[OFF_LOGAVG + r * 32 + c] * (1.f / (float)BATCH);
    W1[r][c] = (r == c) ? 1.f : 0.f;
  }
  __syncthreads();
  for (int j = EXP_TERMS; j >= 1; --j) {
    mm64(W3, W0, W1, lane);
    const float inv = 1.f / (float)j;
#pragma unroll
    for (int i = 0; i < 16; ++i) {
      int r = 16 * h + i;
      W1[r][c] = ((r == c) ? 1.f : 0.f) + W3[r][c] * inv;
    }
    __syncthreads();
  }
#pragma unroll
  for (int i = 0; i < 16; ++i) { int r = 16 * h + i; W2[r][c] = wsf[OFF_S0 + r * 32 + c]; }
  __syncthreads();
  mm64(W3, W2, W1, lane);
  mm64(W0, W3, W2, lane);
  float tr = 0.f;
#pragma unroll
  for (int k = 0; k < 32; ++k) tr += W0[k][k];
  tr *= (1.f / 32.f);
  const float itr = 1.f / tr;
#pragma unroll
  for (int i = 0; i < 16; ++i) {
    int r = 16 * h + i;
    W1[r][c] = W0[r][c] * itr;
    W2[r][c] = (r == c) ? 1.f : 0.f;
  }
  __syncthreads();
  LdsMat Y = W1, Z = W2, Ya = W0, Za = W4;
  ns_sqrt(Y, Z, Ya, Za, W3, lane);
  const float rs = rsqrtf(tr);
#pragma unroll
  for (int i = 0; i < 16; ++i) { int r = 16 * h + i; wsf[OFF_INVS + r * 32 + c] = Z[r][c] * rs; }
  __syncthreads();
  float tr2 = 0.f;
#pragma unroll
  for (int k = 0; k < 32; ++k) tr2 += shift[33 * k];
  tr2 *= (1.f / 32.f);
  const float itr2 = 1.f / tr2;
#pragma unroll
  for (int i = 0; i < 16; ++i) {
    int r = 16 * h + i;
    W1[r][c] = shift[r * 32 + c] * itr2;
    W2[r][c] = (r == c) ? 1.f : 0.f;
  }
  __syncthreads();
  LdsMat Y2 = W1, Z2 = W2, Ya2 = W0, Za2 = W4;
  ns_sqrt(Y2, Z2, Ya2, Za2, W3, lane);
  const float sq2 = sqrtf(tr2);
#pragma unroll
  for (int i = 0; i < 16; ++i) { int r = 16 * h + i; wsf[OFF_SSQRT + r * 32 + c] = Y2[r][c] * sq2; }
}

// BN whiten: L_b = log(inv_s x_b inv_s) -> d_out (scratch); var += ||L_b||_F^2
extern "C" __global__ void __launch_bounds__(64, 3)
spdbn_kC(const float* __restrict__ x, float* __restrict__ wsf, float* __restrict__ outL) {
  __shared__ alignas(16) u16t A0h[32][40], A0l[32][40], A1h[32][40], A1l[32][40];
  __shared__ float chS[NCHEB];
  const int lane = threadIdx.x;
  const int g = lane >> 4, c15 = lane & 15;
  if (lane < NCHEB) chS[lane] = wsf[OFF_CHEB + lane];
  short8 S_h[2], S_l[2];
  load_sym_frags(wsf + OFF_INVS, c15, g, S_h, S_l);
  __syncthreads();
  float ss = 0.f;
  f32x4 L[2][2];
  for (int b = blockIdx.x; b < BATCH; b += MAIN_BLOCKS) {
    whiten_cheb<false>(x + (size_t)b * 1024, S_h, S_l, A0h, A0l, A1h, A1l, chS, g, c15, L);
    float* ob = outL + (size_t)b * 1024;
#pragma unroll
    for (int i = 0; i < 2; ++i)
#pragma unroll
      for (int j = 0; j < 2; ++j)
#pragma unroll
        for (int r = 0; r < 4; ++r) {
          float v = L[i][j][r];
          ob[(16 * i + 4 * g + r) * 32 + 16 * j + c15] = v;
          ss = fmaf(v, v, ss);
        }
    __syncthreads();
  }
#pragma unroll
  for (int off = 32; off >= 1; off >>= 1) ss += __shfl_xor(ss, off);
  if (lane == 0) atomicAdd(&wsf[OFF_VAR], ss);
}

extern "C" __global__ void spdbn_kS3(float* __restrict__ wsf, const float* __restrict__ scale) {
  if (threadIdx.x == 0) {
    float var = wsf[OFF_VAR] * (1.f / (float)BATCH);
    float stdv = sqrtf(var);
    wsf[OFF_P] = scale[0] / (stdv + 1e-5f);
  }
}

// out = s_sqrt * exp(p*L) * s_sqrt  (reads L from d_out, overwrites in place)
extern "C" __global__ void __launch_bounds__(64, 3)
spdbn_kD(float* __restrict__ out, const float* __restrict__ wsf) {
  __shared__ alignas(16) u16t A0h[32][40], A0l[32][40], A1h[32][40], A1l[32][40];
  const int lane = threadIdx.x;
  const int g = lane >> 4, c15 = lane & 15;
  short8 Q_h[2], Q_l[2];
  load_sym_frags(wsf + OFF_SSQRT, c15, g, Q_h, Q_l);
  const float p = wsf[OFF_P];
  const f32x4 z4 = {0.f, 0.f, 0.f, 0.f};
  for (int b = blockIdx.x; b < BATCH; b += MAIN_BLOCKS) {
    float* ob = out + (size_t)b * 1024;
    // stage M = p*L (symmetric) into A0
#pragma unroll
    for (int e = 0; e < 4; ++e) {
      int idx = e * 256 + lane * 4;
      float4 v = *reinterpret_cast<const float4*>(ob + idx);
      int row = idx >> 5, col = idx & 31;
      us4 hv, lv; u16t h, l;
      splitf(v.x * p, h, l); hv[0] = h; lv[0] = l;
      splitf(v.y * p, h, l); hv[1] = h; lv[1] = l;
      splitf(v.z * p, h, l); hv[2] = h; lv[2] = l;
      splitf(v.w * p, h, l); hv[3] = h; lv[3] = l;
      *reinterpret_cast<us4*>(&A0h[row][col]) = hv;
      *reinterpret_cast<us4*>(&A0l[row][col]) = lv;
    }
    __syncthreads();
    short8 Ma_h[2], Ma_l[2];
#pragma unroll
    for (int t = 0; t < 2; ++t) { Ma_h[t] = fragr(A0h, t, c15, g); Ma_l[t] = fragr(A0l, t, c15, g); }
    // P = I staged into A1
#pragma unroll
    for (int i = 0; i < 2; ++i)
#pragma unroll
      for (int j = 0; j < 2; ++j) {
        f32x4 v;
#pragma unroll
        for (int r = 0; r < 4; ++r) v[r] = ((16 * i + 4 * g + r) == (16 * j + c15)) ? 1.f : 0.f;
        stage4(A1h, A1l, i, j, g, c15, v);
      }
    __syncthreads();
    // P = I + (M/j) P, j = 12..1   (ping-pong A1 <-> A0; M hoisted in regs)
    f32x4 acc[2][2];
    int t = 0;
    for (int jj = EXP_TERMS; jj >= 1; --jj, ++t) {
      u16t (*Rh)[40] = (t & 1) ? A0h : A1h;
      u16t (*Rl)[40] = (t & 1) ? A0l : A1l;
      u16t (*Wh)[40] = (t & 1) ? A1h : A0h;
      u16t (*Wl)[40] = (t & 1) ? A1l : A0l;
#pragma unroll
      for (int j = 0; j < 2; ++j) {
        short8 Bh = fragr(Rh, j, c15, g), Bl = fragr(Rl, j, c15, g);
#pragma unroll
        for (int i = 0; i < 2; ++i) {
          f32x4 a = z4;
          a = MFMA16(Ma_l[i], Bh, a);
          a = MFMA16(Ma_h[i], Bl, a);
          a = MFMA16(Ma_h[i], Bh, a);
          acc[i][j] = a;
        }
      }
      const float inv = 1.f / (float)jj;
      __syncthreads();
#pragma unroll
      for (int i = 0; i < 2; ++i)
#pragma unroll
        for (int j = 0; j < 2; ++j) {
          f32x4 v;
#pragma unroll
          for (int r = 0; r < 4; ++r)
            v[r] = fmaf(acc[i][j][r], inv, ((16 * i + 4 * g + r) == (16 * j + c15)) ? 1.f : 0.f);
          stage4(Wh, Wl, i, j, g, c15, v);
        }
      __syncthreads();
    }
    // final P is in A1 (12 iterations: last write t=11 -> A1)
    short8 Pa_h[2], Pa_l[2];
#pragma unroll
    for (int tt = 0; tt < 2; ++tt) { Pa_h[tt] = fragr(A1h, tt, c15, g); Pa_l[tt] = fragr(A1l, tt, c15, g); }
    // W = P * Ssq  -> stage col-major into A0
#pragma unroll
    for (int i = 0; i < 2; ++i)
#pragma unroll
      for (int j = 0; j < 2; ++j) {
        f32x4 a = z4;
        a = MFMA16(Pa_l[i], Q_h[j], a);
        a = MFMA16(Pa_h[i], Q_l[j], a);
        a = MFMA16(Pa_h[i], Q_h[j], a);
        acc[i][j] = a;
      }
    __syncthreads();
#pragma unroll
    for (int i = 0; i < 2; ++i)
#pragma unroll
      for (int j = 0; j < 2; ++j) stage4(A0h, A0l, i, j, g, c15, acc[i][j]);
    __syncthreads();
    // out = Ssq * W
#pragma unroll
    for (int j = 0; j < 2; ++j) {
      short8 Bh = fragr(A0h, j, c15, g), Bl = fragr(A0l, j, c15, g);
#pragma unroll
      for (int i = 0; i < 2; ++i) {
        f32x4 a = z4;
        a = MFMA16(Q_l[i], Bh, a);
        a = MFMA16(Q_h[i], Bl, a);
        a = MFMA16(Q_h[i], Bh, a);
        acc[i][j] = a;
      }
    }
#pragma unroll
    for (int i = 0; i < 2; ++i)
#pragma unroll
      for (int j = 0; j < 2; ++j)
#pragma unroll
        for (int r = 0; r < 4; ++r)
          ob[(16 * i + 4 * g + r) * 32 + 16 * j + c15] = acc[i][j][r];
    __syncthreads();
  }
}

extern "C" void kernel_launch(void* const* d_in, const int* in_sizes, int n_in,
                              void* d_out, int out_size, void* d_ws, size_t ws_size,
                              hipStream_t stream) {
  const float* x     = (const float*)d_in[0];
  const float* shift = (const float*)d_in[1];
  const float* scale = (const float*)d_in[2];
  float* out = (float*)d_out;
  float* wsf = (float*)d_ws;

  size_t zbytes = 32768;
  if (ws_size < zbytes) zbytes = ws_size;
  hipMemsetAsync(d_ws, 0, zbytes, stream);

  hipLaunchKernelGGL(spdbn_kA,  dim3(4096), dim3(256), 0, stream, x, wsf);
  hipLaunchKernelGGL(spdbn_kS1, dim3(1),    dim3(64),  0, stream, wsf);
  hipLaunchKernelGGL(spdbn_kB,  dim3(MAIN_BLOCKS), dim3(64), 0, stream, x, wsf);
  hipLaunchKernelGGL(spdbn_kS2, dim3(1),    dim3(64),  0, stream, wsf, shift);
  hipLaunchKernelGGL(spdbn_kC,  dim3(MAIN_BLOCKS), dim3(64), 0, stream, x, wsf, out);
  hipLaunchKernelGGL(spdbn_kS3, dim3(1),    dim3(64),  0, stream, wsf, scale);
  hipLaunchKernelGGL(spdbn_kD,  dim3(MAIN_BLOCKS), dim3(64), 0, stream, out, wsf);
}

// Round 4
// 1274.775 us; speedup vs baseline: 26.3915x; 1.4390x over previous
//
#include <hip/hip_runtime.h>
#include <cstdint>
#include <cstddef>

#define BATCH       65536
#define LDSW        36          // padded LDS row stride for tiny-kernel matrices
#define NCHEB       26          // Chebyshev terms for log on [CALPHA, CBETA]
#define CALPHA      0.2f
#define CBETA       6.0f
#define NS_ITERS    6           // Newton-Schulz sqrt iterations
#define EXP_TERMS   12          // Taylor terms for matrix exp
#define MAIN_BLOCKS 3072        // main kernels: 3072 1-wave blocks (12/CU co-resident)

// ws float offsets
#define OFF_MEAN0   0
#define OFF_INVS0   1024
#define OFF_S0      2048
#define OFF_LOGAVG  3072
#define OFF_INVS    4096
#define OFF_SSQRT   5120
#define OFF_VAR     6144
#define OFF_P       6145
#define OFF_CHEB    6152        // 26 floats

typedef float (*LdsMat)[LDSW];
typedef __attribute__((ext_vector_type(8))) short short8;
typedef __attribute__((ext_vector_type(4))) float f32x4;
typedef unsigned short u16t;
typedef unsigned int   u32t;

#define MFMA16(a, b, c) __builtin_amdgcn_mfma_f32_16x16x32_bf16((a), (b), (c), 0, 0, 0)

// ---------------- bf16 pack / split helpers (perm-based, 3 ops/dword) ----------------
// pack2_rn: [bf16_rn(b) | bf16_rn(a)] in one dword (round-to-nearest, ties-away)
__device__ __forceinline__ u32t pack2_rn(float a, float b) {
  u32t ua = __float_as_uint(a) + 0x8000u;
  u32t ub = __float_as_uint(b) + 0x8000u;
  return __builtin_amdgcn_perm(ub, ua, 0x07060302u);
}
// split2: hi = rn-bf16 pair (dword), lo = truncated-bf16 pair of the residual
__device__ __forceinline__ void split2(float a, float b, u32t& hw, u32t& lw) {
  u32t ua = __float_as_uint(a) + 0x8000u;
  u32t ub = __float_as_uint(b) + 0x8000u;
  hw = __builtin_amdgcn_perm(ub, ua, 0x07060302u);
  float ra = a - __uint_as_float(ua & 0xFFFF0000u);
  float rb = b - __uint_as_float(ub & 0xFFFF0000u);
  lw = __builtin_amdgcn_perm(__float_as_uint(rb), __float_as_uint(ra), 0x07060302u);
}

// Fragment read from col-major-staged [32][40] u16 array: row 16t+c15, k0 = 8g
__device__ __forceinline__ short8 fragr(const u16t (*G)[40], int t, int c15, int g) {
  return *reinterpret_cast<const short8*>(&G[16 * t + c15][8 * g]);
}
// Stage C-layout tile (4 f32, rows 16i+4g..+3, col 16j+c15): col = 16j+c15, row = 16i+4g
__device__ __forceinline__ void stg_single(u16t (*G)[40], int col, int row, f32x4 v) {
  uint2 w; w.x = pack2_rn(v[0], v[1]); w.y = pack2_rn(v[2], v[3]);
  *reinterpret_cast<uint2*>(&G[col][row]) = w;
}
__device__ __forceinline__ void stg_split(u16t (*Gh)[40], u16t (*Gl)[40], int col, int row, f32x4 v) {
  u32t h0, l0, h1, l1;
  split2(v[0], v[1], h0, l0);
  split2(v[2], v[3], h1, l1);
  uint2 hv; hv.x = h0; hv.y = h1;
  uint2 lv; lv.x = l0; lv.y = l1;
  *reinterpret_cast<uint2*>(&Gh[col][row]) = hv;
  *reinterpret_cast<uint2*>(&Gl[col][row]) = lv;
}

// legacy scalar split (used only in once-per-kernel frag loads)
__device__ __forceinline__ void splitf(float a, u16t& h, u16t& l) {
  unsigned u  = __float_as_uint(a);
  unsigned uh = (u + 0x8000u) & 0xFFFF0000u;
  float    r  = a - __uint_as_float(uh);
  unsigned ul = __float_as_uint(r) + 0x8000u;
  h = (u16t)(uh >> 16);
  l = (u16t)(ul >> 16);
}

// Load hi/lo fragments of a symmetric 32x32 f32 matrix from global (ws).
__device__ __forceinline__ void load_sym_frags(const float* base, int c15, int g,
                                               short8* Fh, short8* Fl) {
#pragma unroll
  for (int t = 0; t < 2; ++t) {
    const float* sp = base + (16 * t + c15) * 32 + 8 * g;
    short8 hh, ll;
#pragma unroll
    for (int j = 0; j < 8; ++j) {
      u16t h, l;
      splitf(sp[j], h, l);
      hh[j] = (short)h;
      ll[j] = (short)l;
    }
    Fh[t] = hh;
    Fl[t] = ll;
  }
}

// ---------------- MFMA whiten + Chebyshev-log core ----------------
// L = cheb_log( g*(S x S) - m*I ).  A-side (2*Ytilde) kept split hi/lo; the
// recurrence B-operand (T_{k-1}) is single rn-bf16; -T_{k-2} folded into MFMA C.
template <bool ACCUM>
__device__ __forceinline__ void whiten_cheb(
    const float* __restrict__ xb, const short8* S_h, const short8* S_l,
    u16t (*Xh)[40], u16t (*Xl)[40], u16t (*Bu0)[40], u16t (*Bu1)[40],
    const float* cof, int g, int c15, const f32x4& dg4, f32x4 (&L)[2][2]) {
  const f32x4 z4 = {0.f, 0.f, 0.f, 0.f};
  const int lane = 16 * g + c15;
  // 1. stage X split into Xh/Xl
#pragma unroll
  for (int e = 0; e < 4; ++e) {
    int idx = e * 256 + lane * 4;
    float4 v = *reinterpret_cast<const float4*>(xb + idx);
    int row = idx >> 5, col = idx & 31;
    u32t h0, l0, h1, l1;
    split2(v.x, v.y, h0, l0);
    split2(v.z, v.w, h1, l1);
    uint2 hv; hv.x = h0; hv.y = h1;
    uint2 lv; lv.x = l0; lv.y = l1;
    *reinterpret_cast<uint2*>(&Xh[row][col]) = hv;
    *reinterpret_cast<uint2*>(&Xl[row][col]) = lv;
  }
  __syncthreads();
  f32x4 acc[2][2];
  // 2. V2 = X * S  (split x split, 3 MFMA/tile) -> stage split into Bu0/Bu1
#pragma unroll
  for (int i = 0; i < 2; ++i) {
    short8 Xa_h = fragr(Xh, i, c15, g), Xa_l = fragr(Xl, i, c15, g);
#pragma unroll
    for (int j = 0; j < 2; ++j) {
      f32x4 a = z4;
      a = MFMA16(Xa_l, S_h[j], a);
      a = MFMA16(Xa_h, S_l[j], a);
      a = MFMA16(Xa_h, S_h[j], a);
      acc[i][j] = a;
    }
  }
  __syncthreads();
#pragma unroll
  for (int i = 0; i < 2; ++i)
#pragma unroll
    for (int j = 0; j < 2; ++j)
      stg_split(Bu0, Bu1, 16 * j + c15, 16 * i + 4 * g, acc[i][j]);
  __syncthreads();
  // 3. Y = S * V2 -> Ytilde
#pragma unroll
  for (int j = 0; j < 2; ++j) {
    short8 Bh = fragr(Bu0, j, c15, g), Bl = fragr(Bu1, j, c15, g);
#pragma unroll
    for (int i = 0; i < 2; ++i) {
      f32x4 a = z4;
      a = MFMA16(S_l[i], Bh, a);
      a = MFMA16(S_h[i], Bl, a);
      a = MFMA16(S_h[i], Bh, a);
      acc[i][j] = a;
    }
  }
  const float GSC = 2.f / (CBETA - CALPHA);
  const float MSH = (CALPHA + CBETA) / (CBETA - CALPHA);
  const float c0 = cof[0], c1 = cof[1];
  f32x4 nTm2[2][2], accB[2][2];
#pragma unroll
  for (int i = 0; i < 2; ++i)
#pragma unroll
    for (int j = 0; j < 2; ++j)
#pragma unroll
      for (int r = 0; r < 4; ++r) {
        float dgf = (i == j) ? dg4[r] : 0.f;
        float yt  = fmaf(acc[i][j][r], GSC, -MSH * dgf);   // Ytilde (= T1)
        accB[i][j][r] = yt;
        nTm2[i][j][r] = -dgf;                              // -T0
        float base = ACCUM ? L[i][j][r] : 0.f;
        L[i][j][r]  = fmaf(c1, yt, fmaf(c0, dgf, base));
      }
  __syncthreads();
  // stage A = 2*Ytilde split -> Xh/Xl (X dead); stage B = T1 single -> Bu0
#pragma unroll
  for (int i = 0; i < 2; ++i)
#pragma unroll
    for (int j = 0; j < 2; ++j) {
      f32x4 y2;
#pragma unroll
      for (int r = 0; r < 4; ++r) y2[r] = accB[i][j][r] + accB[i][j][r];
      stg_split(Xh, Xl, 16 * j + c15, 16 * i + 4 * g, y2);
      stg_single(Bu0, 16 * j + c15, 16 * i + 4 * g, accB[i][j]);
    }
  __syncthreads();
  short8 Yh2[2], Yl2[2];
#pragma unroll
  for (int t = 0; t < 2; ++t) { Yh2[t] = fragr(Xh, t, c15, g); Yl2[t] = fragr(Xl, t, c15, g); }
  // 4. T_k = MFMA(2*Ytilde, T_{k-1}, -T_{k-2});  L += c_k T_k   (pairs, ping-pong)
  f32x4 accA[2][2];
#pragma unroll
  for (int kk = 2; kk < NCHEB; kk += 2) {
    const float cka = cof[kk];
#pragma unroll
    for (int j = 0; j < 2; ++j) {
      short8 Bh = fragr(Bu0, j, c15, g);
#pragma unroll
      for (int i = 0; i < 2; ++i) {
        f32x4 a = nTm2[i][j];
        a = MFMA16(Yl2[i], Bh, a);
        a = MFMA16(Yh2[i], Bh, a);
        accA[i][j] = a;
      }
    }
#pragma unroll
    for (int i = 0; i < 2; ++i)
#pragma unroll
      for (int j = 0; j < 2; ++j)
#pragma unroll
        for (int r = 0; r < 4; ++r) {
          L[i][j][r]    = fmaf(cka, accA[i][j][r], L[i][j][r]);
          nTm2[i][j][r] = -accB[i][j][r];
        }
#pragma unroll
    for (int i = 0; i < 2; ++i)
#pragma unroll
      for (int j = 0; j < 2; ++j)
        stg_single(Bu1, 16 * j + c15, 16 * i + 4 * g, accA[i][j]);
    __syncthreads();
    const float ckb = cof[kk + 1];
#pragma unroll
    for (int j = 0; j < 2; ++j) {
      short8 Bh = fragr(Bu1, j, c15, g);
#pragma unroll
      for (int i = 0; i < 2; ++i) {
        f32x4 a = nTm2[i][j];
        a = MFMA16(Yl2[i], Bh, a);
        a = MFMA16(Yh2[i], Bh, a);
        accB[i][j] = a;
      }
    }
#pragma unroll
    for (int i = 0; i < 2; ++i)
#pragma unroll
      for (int j = 0; j < 2; ++j)
#pragma unroll
        for (int r = 0; r < 4; ++r)
          L[i][j][r] = fmaf(ckb, accB[i][j][r], L[i][j][r]);
    if (kk + 2 < NCHEB) {
#pragma unroll
      for (int i = 0; i < 2; ++i)
#pragma unroll
        for (int j = 0; j < 2; ++j) {
#pragma unroll
          for (int r = 0; r < 4; ++r) nTm2[i][j][r] = -accA[i][j][r];
          stg_single(Bu0, 16 * j + c15, 16 * i + 4 * g, accB[i][j]);
        }
      __syncthreads();
    }
  }
}

// ---------- tiny-kernel helpers (single block, 64 threads; unchanged) ----------

__device__ __forceinline__ float dotrow36(const float* Arow, const float* v) {
  float s = 0.f;
#pragma unroll
  for (int j = 0; j < 8; ++j) {
    float4 a = *reinterpret_cast<const float4*>(Arow + 4 * j);
    s = fmaf(a.x, v[4 * j + 0], s);
    s = fmaf(a.y, v[4 * j + 1], s);
    s = fmaf(a.z, v[4 * j + 2], s);
    s = fmaf(a.w, v[4 * j + 3], s);
  }
  return s;
}

__device__ void mm64(float (*D)[LDSW], const float (*A)[LDSW], const float (*Bm)[LDSW], int lane) {
  const int h = lane >> 5, c = lane & 31;
  float bcol[32];
#pragma unroll
  for (int k = 0; k < 32; ++k) bcol[k] = Bm[k][c];
  float o[16];
#pragma unroll
  for (int i = 0; i < 16; ++i) o[i] = dotrow36(&A[16 * h + i][0], bcol);
  __syncthreads();
#pragma unroll
  for (int i = 0; i < 16; ++i) D[16 * h + i][c] = o[i];
  __syncthreads();
}

__device__ void ns_sqrt(LdsMat& Y, LdsMat& Z, LdsMat& Ya, LdsMat& Za, LdsMat T, int lane) {
  const int h = lane >> 5, c = lane & 31;
  for (int it = 0; it < NS_ITERS; ++it) {
    mm64(T, Z, Y, lane);
#pragma unroll
    for (int i = 0; i < 16; ++i) {
      int r = 16 * h + i;
      T[r][c] = ((r == c) ? 1.5f : 0.f) - 0.5f * T[r][c];
    }
    __syncthreads();
    mm64(Ya, Y, T, lane);
    mm64(Za, T, Z, lane);
    LdsMat t1 = Y; Y = Ya; Ya = t1;
    LdsMat t2 = Z; Z = Za; Za = t2;
  }
}

// ---------- kernels ----------

extern "C" __global__ void __launch_bounds__(256)
spdbn_kA(const float* __restrict__ x, float* __restrict__ wsf) {
  const int e  = (blockIdx.x & 3) * 256 + threadIdx.x;
  const int bs = blockIdx.x >> 2;
  float acc = 0.f;
  for (int t = 0; t < 64; ++t)
    acc += x[(size_t)(bs + 1024 * t) * 1024 + e];
  atomicAdd(&wsf[OFF_MEAN0 + e], acc);
}

extern "C" __global__ void __launch_bounds__(64)
spdbn_kS1(float* __restrict__ wsf) {
  __shared__ alignas(16) float W0[32][LDSW], W1[32][LDSW], W2[32][LDSW], W3[32][LDSW], W4[32][LDSW];
  const int lane = threadIdx.x, h = lane >> 5, c = lane & 31;
  float sacc = 0.f;
#pragma unroll
  for (int k = 0; k < 32; ++k) sacc += wsf[OFF_MEAN0 + 33 * k];
  const float cN = sacc / (32.f * (float)BATCH);
  const float scaleA = 32.f / sacc;
#pragma unroll
  for (int i = 0; i < 16; ++i) {
    int r = 16 * h + i;
    W1[r][c] = wsf[OFF_MEAN0 + r * 32 + c] * scaleA;
    W2[r][c] = (r == c) ? 1.f : 0.f;
  }
  __syncthreads();
  LdsMat Y = W1, Z = W2, Ya = W0, Za = W4;
  ns_sqrt(Y, Z, Ya, Za, W3, lane);
  const float sq = sqrtf(cN), rs = rsqrtf(cN);
#pragma unroll
  for (int i = 0; i < 16; ++i) {
    int r = 16 * h + i;
    wsf[OFF_INVS0 + r * 32 + c] = Z[r][c] * rs;
    wsf[OFF_S0    + r * 32 + c] = Y[r][c] * sq;
  }
  const float PIF = 3.14159265358979f;
  const float th = ((float)lane + 0.5f) * (PIF / 64.f);
  const float t  = 0.5f * (CALPHA + CBETA) + 0.5f * (CBETA - CALPHA) * cosf(th);
  const float fl = logf(t);
  for (int j = 0; j < NCHEB; ++j) {
    float v = fl * cosf((float)j * th) * (2.f / 64.f);
#pragma unroll
    for (int off = 32; off >= 1; off >>= 1) v += __shfl_xor(v, off);
    if (lane == 0) wsf[OFF_CHEB + j] = (j == 0) ? 0.5f * v : v;
  }
}

// Karcher step: accumulate sum_b log(inv_s0 x_b inv_s0)
extern "C" __global__ void __launch_bounds__(64, 3)
spdbn_kB(const float* __restrict__ x, float* __restrict__ wsf) {
  __shared__ alignas(16) u16t Xh[32][40], Xl[32][40], Bu0[32][40], Bu1[32][40];
  const int lane = threadIdx.x;
  const int g = lane >> 4, c15 = lane & 15;
  short8 S_h[2], S_l[2];
  load_sym_frags(wsf + OFF_INVS0, c15, g, S_h, S_l);
  float cof[NCHEB];
#pragma unroll
  for (int k = 0; k < NCHEB; ++k) cof[k] = wsf[OFF_CHEB + k];
  f32x4 dg4;
#pragma unroll
  for (int r = 0; r < 4; ++r) dg4[r] = (4 * g + r == c15) ? 1.f : 0.f;
  f32x4 L[2][2];
#pragma unroll
  for (int i = 0; i < 2; ++i)
#pragma unroll
    for (int j = 0; j < 2; ++j) L[i][j] = (f32x4){0.f, 0.f, 0.f, 0.f};
  for (int b = blockIdx.x; b < BATCH; b += MAIN_BLOCKS) {
    whiten_cheb<true>(x + (size_t)b * 1024, S_h, S_l, Xh, Xl, Bu0, Bu1, cof, g, c15, dg4, L);
    __syncthreads();
  }
#pragma unroll
  for (int i = 0; i < 2; ++i)
#pragma unroll
    for (int j = 0; j < 2; ++j)
#pragma unroll
      for (int r = 0; r < 4; ++r)
        atomicAdd(&wsf[OFF_LOGAVG + (16 * i + 4 * g + r) * 32 + 16 * j + c15], L[i][j][r]);
}

extern "C" __global__ void __launch_bounds__(64)
spdbn_kS2(float* __restrict__ wsf, const float* __restrict__ shift) {
  __shared__ alignas(16) float W0[32][LDSW], W1[32][LDSW], W2[32][LDSW], W3[32][LDSW], W4[32][LDSW];
  const int lane = threadIdx.x, h = lane >> 5, c = lane & 31;
#pragma unroll
  for (int i = 0; i < 16; ++i) {
    int r = 16 * h + i;
    W0[r][c] = wsf[OFF_LOGAVG + r * 32 + c] * (1.f / (float)BATCH);
    W1[r][c] = (r == c) ? 1.f : 0.f;
  }
  __syncthreads();
  for (int j = EXP_TERMS; j >= 1; --j) {
    mm64(W3, W0, W1, lane);
    const float inv = 1.f / (float)j;
#pragma unroll
    for (int i = 0; i < 16; ++i) {
      int r = 16 * h + i;
      W1[r][c] = ((r == c) ? 1.f : 0.f) + W3[r][c] * inv;
    }
    __syncthreads();
  }
#pragma unroll
  for (int i = 0; i < 16; ++i) { int r = 16 * h + i; W2[r][c] = wsf[OFF_S0 + r * 32 + c]; }
  __syncthreads();
  mm64(W3, W2, W1, lane);
  mm64(W0, W3, W2, lane);
  float tr = 0.f;
#pragma unroll
  for (int k = 0; k < 32; ++k) tr += W0[k][k];
  tr *= (1.f / 32.f);
  const float itr = 1.f / tr;
#pragma unroll
  for (int i = 0; i < 16; ++i) {
    int r = 16 * h + i;
    W1[r][c] = W0[r][c] * itr;
    W2[r][c] = (r == c) ? 1.f : 0.f;
  }
  __syncthreads();
  LdsMat Y = W1, Z = W2, Ya = W0, Za = W4;
  ns_sqrt(Y, Z, Ya, Za, W3, lane);
  const float rs = rsqrtf(tr);
#pragma unroll
  for (int i = 0; i < 16; ++i) { int r = 16 * h + i; wsf[OFF_INVS + r * 32 + c] = Z[r][c] * rs; }
  __syncthreads();
  float tr2 = 0.f;
#pragma unroll
  for (int k = 0; k < 32; ++k) tr2 += shift[33 * k];
  tr2 *= (1.f / 32.f);
  const float itr2 = 1.f / tr2;
#pragma unroll
  for (int i = 0; i < 16; ++i) {
    int r = 16 * h + i;
    W1[r][c] = shift[r * 32 + c] * itr2;
    W2[r][c] = (r == c) ? 1.f : 0.f;
  }
  __syncthreads();
  LdsMat Y2 = W1, Z2 = W2, Ya2 = W0, Za2 = W4;
  ns_sqrt(Y2, Z2, Ya2, Za2, W3, lane);
  const float sq2 = sqrtf(tr2);
#pragma unroll
  for (int i = 0; i < 16; ++i) { int r = 16 * h + i; wsf[OFF_SSQRT + r * 32 + c] = Y2[r][c] * sq2; }
}

// BN whiten: L_b = log(inv_s x_b inv_s) -> d_out (scratch); var += ||L_b||_F^2
extern "C" __global__ void __launch_bounds__(64, 3)
spdbn_kC(const float* __restrict__ x, float* __restrict__ wsf, float* __restrict__ outL) {
  __shared__ alignas(16) u16t Xh[32][40], Xl[32][40], Bu0[32][40], Bu1[32][40];
  const int lane = threadIdx.x;
  const int g = lane >> 4, c15 = lane & 15;
  short8 S_h[2], S_l[2];
  load_sym_frags(wsf + OFF_INVS, c15, g, S_h, S_l);
  float cof[NCHEB];
#pragma unroll
  for (int k = 0; k < NCHEB; ++k) cof[k] = wsf[OFF_CHEB + k];
  f32x4 dg4;
#pragma unroll
  for (int r = 0; r < 4; ++r) dg4[r] = (4 * g + r == c15) ? 1.f : 0.f;
  float ss = 0.f;
  f32x4 L[2][2];
  for (int b = blockIdx.x; b < BATCH; b += MAIN_BLOCKS) {
    whiten_cheb<false>(x + (size_t)b * 1024, S_h, S_l, Xh, Xl, Bu0, Bu1, cof, g, c15, dg4, L);
    float* ob = outL + (size_t)b * 1024;
#pragma unroll
    for (int i = 0; i < 2; ++i)
#pragma unroll
      for (int j = 0; j < 2; ++j)
#pragma unroll
        for (int r = 0; r < 4; ++r) {
          float v = L[i][j][r];
          ob[(16 * i + 4 * g + r) * 32 + 16 * j + c15] = v;
          ss = fmaf(v, v, ss);
        }
    __syncthreads();
  }
#pragma unroll
  for (int off = 32; off >= 1; off >>= 1) ss += __shfl_xor(ss, off);
  if (lane == 0) atomicAdd(&wsf[OFF_VAR], ss);
}

extern "C" __global__ void spdbn_kS3(float* __restrict__ wsf, const float* __restrict__ scale) {
  if (threadIdx.x == 0) {
    float var = wsf[OFF_VAR] * (1.f / (float)BATCH);
    float stdv = sqrtf(var);
    wsf[OFF_P] = scale[0] / (stdv + 1e-5f);
  }
}

// out = s_sqrt * exp(p*L) * s_sqrt  (reads L from d_out, overwrites in place)
extern "C" __global__ void __launch_bounds__(64, 3)
spdbn_kD(float* __restrict__ out, const float* __restrict__ wsf) {
  __shared__ alignas(16) u16t Xh[32][40], Xl[32][40], Bu0[32][40], Bu1[32][40];
  const int lane = threadIdx.x;
  const int g = lane >> 4, c15 = lane & 15;
  short8 Q_h[2], Q_l[2];
  load_sym_frags(wsf + OFF_SSQRT, c15, g, Q_h, Q_l);
  const float p = wsf[OFF_P];
  const f32x4 z4 = {0.f, 0.f, 0.f, 0.f};
  f32x4 dg4;
#pragma unroll
  for (int r = 0; r < 4; ++r) dg4[r] = (4 * g + r == c15) ? 1.f : 0.f;
  // identity tile packed dwords (constant per lane)
  uint2 idp; idp.x = pack2_rn(dg4[0], dg4[1]); idp.y = pack2_rn(dg4[2], dg4[3]);
  uint2 zp;  zp.x = 0u; zp.y = 0u;
  for (int b = blockIdx.x; b < BATCH; b += MAIN_BLOCKS) {
    float* ob = out + (size_t)b * 1024;
    // stage M = p*L split -> Xh/Xl
#pragma unroll
    for (int e = 0; e < 4; ++e) {
      int idx = e * 256 + lane * 4;
      float4 v = *reinterpret_cast<const float4*>(ob + idx);
      int row = idx >> 5, col = idx & 31;
      u32t h0, l0, h1, l1;
      split2(v.x * p, v.y * p, h0, l0);
      split2(v.z * p, v.w * p, h1, l1);
      uint2 hv; hv.x = h0; hv.y = h1;
      uint2 lv; lv.x = l0; lv.y = l1;
      *reinterpret_cast<uint2*>(&Xh[row][col]) = hv;
      *reinterpret_cast<uint2*>(&Xl[row][col]) = lv;
    }
    // P = I staged single-bf16 into Bu0
#pragma unroll
    for (int i = 0; i < 2; ++i)
#pragma unroll
      for (int j = 0; j < 2; ++j)
        *reinterpret_cast<uint2*>(&Bu0[16 * j + c15][16 * i + 4 * g]) = (i == j) ? idp : zp;
    __syncthreads();
    short8 Mh[2], Ml[2];
#pragma unroll
    for (int t = 0; t < 2; ++t) { Mh[t] = fragr(Xh, t, c15, g); Ml[t] = fragr(Xl, t, c15, g); }
    // Taylor: P = I + (M/jj) P, jj = 12..2 (single-bf16 B, split M)
    f32x4 acc[2][2];
#pragma unroll
    for (int jj = EXP_TERMS; jj >= 2; --jj) {
      const int t = EXP_TERMS - jj;
      const u16t (*R)[40] = (t & 1) ? Bu1 : Bu0;
      u16t (*W)[40]       = (t & 1) ? Bu0 : Bu1;
#pragma unroll
      for (int j = 0; j < 2; ++j) {
        short8 Bh = fragr(R, j, c15, g);
#pragma unroll
        for (int i = 0; i < 2; ++i) {
          f32x4 a = z4;
          a = MFMA16(Ml[i], Bh, a);
          a = MFMA16(Mh[i], Bh, a);
          acc[i][j] = a;
        }
      }
      const float inv = 1.f / (float)jj;
#pragma unroll
      for (int i = 0; i < 2; ++i)
#pragma unroll
        for (int j = 0; j < 2; ++j) {
          f32x4 v;
#pragma unroll
          for (int r = 0; r < 4; ++r)
            v[r] = fmaf(acc[i][j][r], inv, (i == j) ? dg4[r] : 0.f);
          stg_single(W, 16 * j + c15, 16 * i + 4 * g, v);
        }
      __syncthreads();
    }
    // final jj=1 in f32: Pf = I + M*P  (read Bu1), stage split -> Xh/Xl (M dead)
#pragma unroll
    for (int j = 0; j < 2; ++j) {
      short8 Bh = fragr(Bu1, j, c15, g);
#pragma unroll
      for (int i = 0; i < 2; ++i) {
        f32x4 a = z4;
        a = MFMA16(Ml[i], Bh, a);
        a = MFMA16(Mh[i], Bh, a);
        acc[i][j] = a;
      }
    }
    __syncthreads();
#pragma unroll
    for (int i = 0; i < 2; ++i)
#pragma unroll
      for (int j = 0; j < 2; ++j) {
        f32x4 v;
#pragma unroll
        for (int r = 0; r < 4; ++r)
          v[r] = acc[i][j][r] + ((i == j) ? dg4[r] : 0.f);
        stg_split(Xh, Xl, 16 * j + c15, 16 * i + 4 * g, v);
      }
    __syncthreads();
    short8 Ph[2], Pl[2];
#pragma unroll
    for (int t = 0; t < 2; ++t) { Ph[t] = fragr(Xh, t, c15, g); Pl[t] = fragr(Xl, t, c15, g); }
    // W = P * Ssq (split x split) -> stage split -> Bu0/Bu1
#pragma unroll
    for (int i = 0; i < 2; ++i)
#pragma unroll
      for (int j = 0; j < 2; ++j) {
        f32x4 a = z4;
        a = MFMA16(Pl[i], Q_h[j], a);
        a = MFMA16(Ph[i], Q_l[j], a);
        a = MFMA16(Ph[i], Q_h[j], a);
        acc[i][j] = a;
      }
    __syncthreads();
#pragma unroll
    for (int i = 0; i < 2; ++i)
#pragma unroll
      for (int j = 0; j < 2; ++j)
        stg_split(Bu0, Bu1, 16 * j + c15, 16 * i + 4 * g, acc[i][j]);
    __syncthreads();
    // out = Ssq * W
#pragma unroll
    for (int j = 0; j < 2; ++j) {
      short8 Wh = fragr(Bu0, j, c15, g), Wl = fragr(Bu1, j, c15, g);
#pragma unroll
      for (int i = 0; i < 2; ++i) {
        f32x4 a = z4;
        a = MFMA16(Q_l[i], Wh, a);
        a = MFMA16(Q_h[i], Wl, a);
        a = MFMA16(Q_h[i], Wh, a);
        acc[i][j] = a;
      }
    }
#pragma unroll
    for (int i = 0; i < 2; ++i)
#pragma unroll
      for (int j = 0; j < 2; ++j)
#pragma unroll
        for (int r = 0; r < 4; ++r)
          ob[(16 * i + 4 * g + r) * 32 + 16 * j + c15] = acc[i][j][r];
    __syncthreads();
  }
}

extern "C" void kernel_launch(void* const* d_in, const int* in_sizes, int n_in,
                              void* d_out, int out_size, void* d_ws, size_t ws_size,
                              hipStream_t stream) {
  const float* x     = (const float*)d_in[0];
  const float* shift = (const float*)d_in[1];
  const float* scale = (const float*)d_in[2];
  float* out = (float*)d_out;
  float* wsf = (float*)d_ws;

  size_t zbytes = 32768;
  if (ws_size < zbytes) zbytes = ws_size;
  hipMemsetAsync(d_ws, 0, zbytes, stream);

  hipLaunchKernelGGL(spdbn_kA,  dim3(4096), dim3(256), 0, stream, x, wsf);
  hipLaunchKernelGGL(spdbn_kS1, dim3(1),    dim3(64),  0, stream, wsf);
  hipLaunchKernelGGL(spdbn_kB,  dim3(MAIN_BLOCKS), dim3(64), 0, stream, x, wsf);
  hipLaunchKernelGGL(spdbn_kS2, dim3(1),    dim3(64),  0, stream, wsf, shift);
  hipLaunchKernelGGL(spdbn_kC,  dim3(MAIN_BLOCKS), dim3(64), 0, stream, x, wsf, out);
  hipLaunchKernelGGL(spdbn_kS3, dim3(1),    dim3(64),  0, stream, wsf, scale);
  hipLaunchKernelGGL(spdbn_kD,  dim3(MAIN_BLOCKS), dim3(64), 0, stream, out, wsf);
}